// Round 1
// baseline (1671.080 us; speedup 1.0000x reference)
//
#include <hip/hip_runtime.h>

// Problem constants (from reference)
#define NROWS 131072          // 32*64*64 flattened rows
#define NELEM 8388608         // NROWS * 64
#define DDIM  64
#define KCODES 1024

__device__ __forceinline__ float4 ld4(const float* p, int off) {
  return *reinterpret_cast<const float4*>(p + off);
}
__device__ __forceinline__ void st4(float* p, int off, float4 v) {
  *reinterpret_cast<float4*>(p + off) = v;
}
__device__ __forceinline__ float fma4(float4 a, float4 b, float acc) {
  acc = fmaf(a.x, b.x, acc); acc = fmaf(a.y, b.y, acc);
  acc = fmaf(a.z, b.z, acc); acc = fmaf(a.w, b.w, acc);
  return acc;
}
__device__ __forceinline__ float4 fma4s(float4 acc, float4 b, float s) {
  acc.x = fmaf(b.x, s, acc.x); acc.y = fmaf(b.y, s, acc.y);
  acc.z = fmaf(b.z, s, acc.z); acc.w = fmaf(b.w, s, acc.w);
  return acc;
}

// Stage a 64x64 fp32 tile (contiguous in global) into LDS with quad swizzle
// physical quad p = dq ^ (row>>2); conflict-free coalesced float4 loads.
__device__ __forceinline__ void stage64(float* lds, const float* gsrc, int tid) {
  const float4* g4 = reinterpret_cast<const float4*>(gsrc);
  #pragma unroll
  for (int j = 0; j < 4; ++j) {
    int g = tid + (j << 8);
    int row = g >> 4, dq = g & 15;
    int p = dq ^ (row >> 2);
    st4(lds, (row << 6) + (p << 2), g4[g]);
  }
}

// ---------------- kernel 0: ||e_k||^2 ----------------
__global__ void k_enorm(const float* __restrict__ emb, float* __restrict__ enorm2) {
  int k = blockIdx.x * blockDim.x + threadIdx.x;   // 0..1023
  const float4* e4 = reinterpret_cast<const float4*>(emb) + k * 16;
  float s = 0.f;
  #pragma unroll
  for (int i = 0; i < 16; ++i) { float4 v = e4[i]; s = fma4(v, v, s); }
  enorm2[k] = s;
}

// Shared score micro-GEMM: 64 rows x 64 local-k, thread owns (4 rows, 4 k)
__device__ __forceinline__ void score16(const float* xs, const float* es,
                                        int rq, int kq, float acc[4][4]) {
  #pragma unroll
  for (int jr = 0; jr < 4; ++jr)
    #pragma unroll
    for (int jk = 0; jk < 4; ++jk) acc[jr][jk] = 0.f;
  #pragma unroll
  for (int dq = 0; dq < 16; ++dq) {
    float4 xv[4], ev[4];
    #pragma unroll
    for (int jr = 0; jr < 4; ++jr)
      xv[jr] = ld4(xs, (((rq << 2) + jr) << 6) + ((dq ^ rq) << 2));
    #pragma unroll
    for (int jk = 0; jk < 4; ++jk)
      ev[jk] = ld4(es, (((kq << 2) + jk) << 6) + ((dq ^ kq) << 2));
    #pragma unroll
    for (int jr = 0; jr < 4; ++jr)
      #pragma unroll
      for (int jk = 0; jk < 4; ++jk)
        acc[jr][jk] = fma4(xv[jr], ev[jk], acc[jr][jk]);
  }
}

// ---------------- kernel 1: stats + enc + quant + counts + sq ----------------
__global__ __launch_bounds__(256, 3)
void k_main(const float* __restrict__ x, const float* __restrict__ emb,
            const float* __restrict__ temp, const float* __restrict__ enorm2,
            float* __restrict__ ml, float* __restrict__ counts_g,
            float* __restrict__ sq_g, float* __restrict__ out)
{
  __shared__ float xs[64 * 64];
  __shared__ float es[64 * 64];
  __shared__ float encs[64 * 64];
  __shared__ float cnt_lds[KCODES];

  const int tid = threadIdx.x;
  const int row_base = blockIdx.x << 6;
  const float invT = 1.0f / temp[0];

  #pragma unroll
  for (int j = 0; j < 4; ++j) cnt_lds[tid + (j << 8)] = 0.0f;

  stage64(xs, x + row_base * 64, tid);

  const int kq = tid & 15;
  const int rq = tid >> 4;
  const int r0 = rq << 2;

  float m[4], l[4];
  #pragma unroll
  for (int jr = 0; jr < 4; ++jr) { m[jr] = -3.0e38f; l[jr] = 0.0f; }

  // ---------- pass 1: online softmax stats over 16 chunks of 64 codes ----------
  for (int c = 0; c < 16; ++c) {
    __syncthreads();                    // es safe to overwrite
    stage64(es, emb + (c << 6) * 64, tid);
    __syncthreads();

    float acc[4][4];
    score16(xs, es, rq, kq, acc);
    float4 en2 = *reinterpret_cast<const float4*>(enorm2 + (c << 6) + (kq << 2));
    #pragma unroll
    for (int jr = 0; jr < 4; ++jr) {
      float s0 = fmaf(2.f, acc[jr][0], -en2.x) * invT;
      float s1 = fmaf(2.f, acc[jr][1], -en2.y) * invT;
      float s2 = fmaf(2.f, acc[jr][2], -en2.z) * invT;
      float s3 = fmaf(2.f, acc[jr][3], -en2.w) * invT;
      float cm = fmaxf(fmaxf(s0, s1), fmaxf(s2, s3));
      #pragma unroll
      for (int off = 1; off < 16; off <<= 1) cm = fmaxf(cm, __shfl_xor(cm, off, 16));
      float cl = __expf(s0 - cm) + __expf(s1 - cm) + __expf(s2 - cm) + __expf(s3 - cm);
      #pragma unroll
      for (int off = 1; off < 16; off <<= 1) cl += __shfl_xor(cl, off, 16);
      float mn = fmaxf(m[jr], cm);
      l[jr] = l[jr] * __expf(m[jr] - mn) + cl * __expf(cm - mn);
      m[jr] = mn;
    }
  }

  float rl[4];
  #pragma unroll
  for (int jr = 0; jr < 4; ++jr) rl[jr] = 1.0f / l[jr];
  if (kq == 0) {
    #pragma unroll
    for (int jr = 0; jr < 4; ++jr) {
      int r = row_base + r0 + jr;
      ml[2 * r] = m[jr];
      ml[2 * r + 1] = l[jr];
    }
  }

  // ---------- pass 2: enc -> quant / counts ----------
  float4 qacc[4];
  #pragma unroll
  for (int jr = 0; jr < 4; ++jr) qacc[jr] = make_float4(0.f, 0.f, 0.f, 0.f);
  const int dqv = tid & 15;   // d-quad owned in PV phase (rows same as rq)

  for (int c = 0; c < 16; ++c) {
    __syncthreads();                    // es+encs safe to overwrite
    stage64(es, emb + (c << 6) * 64, tid);
    __syncthreads();

    float acc[4][4];
    score16(xs, es, rq, kq, acc);
    float4 en2 = *reinterpret_cast<const float4*>(enorm2 + (c << 6) + (kq << 2));
    float enc[4][4];
    #pragma unroll
    for (int jr = 0; jr < 4; ++jr) {
      enc[jr][0] = __expf(fmaf(2.f, acc[jr][0], -en2.x) * invT - m[jr]) * rl[jr];
      enc[jr][1] = __expf(fmaf(2.f, acc[jr][1], -en2.y) * invT - m[jr]) * rl[jr];
      enc[jr][2] = __expf(fmaf(2.f, acc[jr][2], -en2.z) * invT - m[jr]) * rl[jr];
      enc[jr][3] = __expf(fmaf(2.f, acc[jr][3], -en2.w) * invT - m[jr]) * rl[jr];
      int r = r0 + jr;
      float4 v = make_float4(enc[jr][0], enc[jr][1], enc[jr][2], enc[jr][3]);
      st4(encs, (r << 6) + ((kq ^ (r & 15)) << 2), v);
    }
    // per-k column sums -> cnt_lds
    #pragma unroll
    for (int jk = 0; jk < 4; ++jk) {
      float v = enc[0][jk] + enc[1][jk] + enc[2][jk] + enc[3][jk];
      v += __shfl_xor(v, 16, 64);
      v += __shfl_xor(v, 32, 64);
      if ((tid & 63) < 16) atomicAdd(&cnt_lds[(c << 6) + (kq << 2) + jk], v);
    }
    __syncthreads();
    // PV: quant += enc @ e  (thread: 4 rows x 1 d-quad)
    #pragma unroll
    for (int kb = 0; kb < 16; ++kb) {
      float4 e4[4];
      #pragma unroll
      for (int jk = 0; jk < 4; ++jk)
        e4[jk] = ld4(es, (((kb << 2) + jk) << 6) + ((dqv ^ kb) << 2));
      #pragma unroll
      for (int jr = 0; jr < 4; ++jr) {
        int r = r0 + jr;
        float4 p4 = ld4(encs, (r << 6) + ((kb ^ (r & 15)) << 2));
        qacc[jr] = fma4s(qacc[jr], e4[0], p4.x);
        qacc[jr] = fma4s(qacc[jr], e4[1], p4.y);
        qacc[jr] = fma4s(qacc[jr], e4[2], p4.z);
        qacc[jr] = fma4s(qacc[jr], e4[3], p4.w);
      }
    }
  }

  // ---------- epilogue: quant_st out, sum((quant-x)^2), counts dump ----------
  float sqp = 0.f;
  #pragma unroll
  for (int jr = 0; jr < 4; ++jr) {
    int r = r0 + jr;
    float4 x4 = ld4(xs, (r << 6) + ((dqv ^ rq) << 2));
    float4 q4 = qacc[jr];
    float4 diff = make_float4(q4.x - x4.x, q4.y - x4.y, q4.z - x4.z, q4.w - x4.w);
    float4 qst = make_float4(x4.x + diff.x, x4.y + diff.y, x4.z + diff.z, x4.w + diff.w);
    reinterpret_cast<float4*>(out)[((row_base + r) << 4) + dqv] = qst;
    sqp += diff.x * diff.x + diff.y * diff.y + diff.z * diff.z + diff.w * diff.w;
  }
  #pragma unroll
  for (int off = 1; off < 64; off <<= 1) sqp += __shfl_xor(sqp, off, 64);
  if ((tid & 63) == 0) atomicAdd(sq_g, sqp);

  __syncthreads();
  #pragma unroll
  for (int j = 0; j < 4; ++j) {
    int k = tid + (j << 8);
    atomicAdd(&counts_g[k], cnt_lds[k]);
  }
}

// ---------------- kernel 2: dw = enc^T @ x (recompute enc from m,l) ----------------
__global__ __launch_bounds__(256, 2)
void k_dw(const float* __restrict__ x, const float* __restrict__ emb,
          const float* __restrict__ temp, const float* __restrict__ enorm2,
          const float* __restrict__ ml, float* __restrict__ dw_g)
{
  __shared__ float es2[128 * 64];
  __shared__ float xs[64 * 64];
  __shared__ float encs2[64 * 128];

  const int tid = threadIdx.x;
  const int ktile = blockIdx.x & 7;     // 8 tiles x 128 codes
  const int nchunk = blockIdx.x >> 3;   // 64 chunks x 2048 rows
  const float invT = 1.0f / temp[0];
  const int kbase = ktile << 7;

  {
    const float4* g4 = reinterpret_cast<const float4*>(emb + (kbase << 6));
    #pragma unroll
    for (int j = 0; j < 8; ++j) {
      int g = tid + (j << 8);
      int row = g >> 4, dq = g & 15;
      int p = dq ^ ((row >> 2) & 15);
      st4(es2, (row << 6) + (p << 2), g4[g]);
    }
  }

  const int kq = tid & 15;   // owns 8 contiguous k (score+dw) ; k0 = 8*kq
  const int rq = tid >> 4;   // owns 4 rows (score) ; d-quad rq (dw)
  const int r0 = rq << 2;

  float en2[8];
  {
    const float* e2 = enorm2 + kbase + (kq << 3);
    #pragma unroll
    for (int jk = 0; jk < 8; ++jk) en2[jk] = e2[jk];
  }

  float4 dwacc[8];
  #pragma unroll
  for (int jk = 0; jk < 8; ++jk) dwacc[jk] = make_float4(0.f, 0.f, 0.f, 0.f);

  const int rows_base = nchunk << 11;   // *2048
  for (int t = 0; t < 32; ++t) {
    const int row_base = rows_base + (t << 6);
    __syncthreads();                    // xs/encs2 safe to overwrite
    stage64(xs, x + row_base * 64, tid);
    float mreg[4], rl[4];
    #pragma unroll
    for (int jr = 0; jr < 4; ++jr) {
      int r = row_base + r0 + jr;
      mreg[jr] = ml[2 * r];
      rl[jr] = 1.0f / ml[2 * r + 1];
    }
    __syncthreads();

    // score 4r x 8k
    float acc[4][8];
    #pragma unroll
    for (int jr = 0; jr < 4; ++jr)
      #pragma unroll
      for (int jk = 0; jk < 8; ++jk) acc[jr][jk] = 0.f;
    #pragma unroll
    for (int dq = 0; dq < 16; ++dq) {
      float4 xv[4], ev[8];
      #pragma unroll
      for (int jr = 0; jr < 4; ++jr)
        xv[jr] = ld4(xs, ((r0 + jr) << 6) + ((dq ^ rq) << 2));
      #pragma unroll
      for (int jk = 0; jk < 8; ++jk) {
        int kk = (kq << 3) + jk;
        ev[jk] = ld4(es2, (kk << 6) + ((dq ^ ((kk >> 2) & 15)) << 2));
      }
      #pragma unroll
      for (int jr = 0; jr < 4; ++jr)
        #pragma unroll
        for (int jk = 0; jk < 8; ++jk)
          acc[jr][jk] = fma4(xv[jr], ev[jk], acc[jr][jk]);
    }
    // enc -> encs2 (quads swizzled: phys = q ^ ((r&15)<<1))
    #pragma unroll
    for (int jr = 0; jr < 4; ++jr) {
      int r = r0 + jr;
      float e[8];
      #pragma unroll
      for (int jk = 0; jk < 8; ++jk)
        e[jk] = __expf(fmaf(2.f, acc[jr][jk], -en2[jk]) * invT - mreg[jr]) * rl[jr];
      int f = (r & 15) << 1;
      st4(encs2, (r << 7) + (((kq << 1) ^ f) << 2), make_float4(e[0], e[1], e[2], e[3]));
      st4(encs2, (r << 7) + ((((kq << 1) + 1) ^ f) << 2), make_float4(e[4], e[5], e[6], e[7]));
    }
    __syncthreads();
    // dw accumulate: thread = (8 k, 1 d-quad = rq)
    #pragma unroll 8
    for (int r = 0; r < 64; ++r) {
      float4 x4 = ld4(xs, (r << 6) + ((rq ^ (r >> 2)) << 2));
      int f = (r & 15) << 1;
      float4 p0 = ld4(encs2, (r << 7) + (((kq << 1) ^ f) << 2));
      float4 p1 = ld4(encs2, (r << 7) + ((((kq << 1) + 1) ^ f) << 2));
      dwacc[0] = fma4s(dwacc[0], x4, p0.x);
      dwacc[1] = fma4s(dwacc[1], x4, p0.y);
      dwacc[2] = fma4s(dwacc[2], x4, p0.z);
      dwacc[3] = fma4s(dwacc[3], x4, p0.w);
      dwacc[4] = fma4s(dwacc[4], x4, p1.x);
      dwacc[5] = fma4s(dwacc[5], x4, p1.y);
      dwacc[6] = fma4s(dwacc[6], x4, p1.z);
      dwacc[7] = fma4s(dwacc[7], x4, p1.w);
    }
  }

  #pragma unroll
  for (int jk = 0; jk < 8; ++jk) {
    int k = kbase + (kq << 3) + jk;
    float* dst = dw_g + k * 64 + (rq << 2);
    atomicAdd(dst + 0, dwacc[jk].x);
    atomicAdd(dst + 1, dwacc[jk].y);
    atomicAdd(dst + 2, dwacc[jk].z);
    atomicAdd(dst + 3, dwacc[jk].w);
  }
}

// ---------------- kernel 3: finalize losses ----------------
__device__ __forceinline__ float blk_sum(float v, float* red4) {
  #pragma unroll
  for (int off = 1; off < 64; off <<= 1) v += __shfl_xor(v, off, 64);
  __syncthreads();
  if ((threadIdx.x & 63) == 0) red4[threadIdx.x >> 6] = v;
  __syncthreads();
  return red4[0] + red4[1] + red4[2] + red4[3];
}

__global__ void k_final(const float* __restrict__ counts_g, const float* __restrict__ dw_g,
                        const float* __restrict__ sq_g,
                        const float* __restrict__ ema_cs, const float* __restrict__ ema_w,
                        const float* __restrict__ usage, float* __restrict__ out)
{
  __shared__ float cs_lds[KCODES];
  __shared__ float red4[4];
  const int t = threadIdx.x;

  float4 c4 = reinterpret_cast<const float4*>(counts_g)[t];
  float4 e4 = reinterpret_cast<const float4*>(ema_cs)[t];
  float4 u4 = reinterpret_cast<const float4*>(usage)[t];
  float cnt[4] = {c4.x, c4.y, c4.z, c4.w};
  float ecs[4] = {e4.x, e4.y, e4.z, e4.w};
  float usg[4] = {u4.x, u4.y, u4.z, u4.w};

  float ncs[4], nu[4];
  float n_p = 0.f, snu_p = 0.f, ent_p = 0.f;
  #pragma unroll
  for (int j = 0; j < 4; ++j) {
    ncs[j] = fmaf(0.99f, ecs[j], 0.01f * cnt[j]);
    n_p += ncs[j];
    nu[j] = fmaf(0.99f, usg[j], 0.01f * cnt[j]);
    snu_p += nu[j];
    float avg = cnt[j] * (1.0f / 131072.0f);
    ent_p -= avg * logf(avg + 1e-10f);
  }
  float n = blk_sum(n_p, red4);
  float snu = blk_sum(snu_p, red4);
  float ent = blk_sum(ent_p, red4);

  float div_p = 0.f;
  float denom = n + 1024.0f * 1e-5f;
  #pragma unroll
  for (int j = 0; j < 4; ++j) {
    float cs = (ncs[j] + 1e-5f) / denom * n;
    cs_lds[(t << 2) + j] = cs;
    float up = nu[j] / (snu + 1e-5f);
    div_p -= up * logf(up + 1e-10f);
  }
  float dvr = blk_sum(div_p, red4);
  __syncthreads();

  float reg_p = 0.f;
  for (int j = 0; j < 256; ++j) {
    int i = t + (j << 8);
    float v = fmaf(0.01f, dw_g[i], 0.99f * ema_w[i]) / cs_lds[i >> 6];
    reg_p = fmaf(v, v, reg_p);
  }
  float reg = blk_sum(reg_p, red4);

  if (t == 0) {
    float mse = sq_g[0] * (1.0f / 8388608.0f);   // q_latent == e_latent numerically
    float loss = 1.25f * mse + reg + 0.8f * (ent + dvr);
    out[NELEM] = loss;
    out[NELEM + 1] = expf(ent);
  }
}

extern "C" void kernel_launch(void* const* d_in, const int* in_sizes, int n_in,
                              void* d_out, int out_size, void* d_ws, size_t ws_size,
                              hipStream_t stream)
{
  const float* x      = (const float*)d_in[0];
  const float* emb    = (const float*)d_in[1];
  const float* temp   = (const float*)d_in[2];
  const float* ema_cs = (const float*)d_in[3];
  const float* ema_w  = (const float*)d_in[4];
  const float* usage  = (const float*)d_in[5];
  float* out = (float*)d_out;
  float* ws  = (float*)d_ws;

  // workspace layout (floats)
  float* counts = ws;             // 1024
  float* dw     = ws + 1024;      // 65536
  float* sq     = ws + 66560;     // 1
  float* enorm2 = ws + 66816;     // 1024 (16B aligned)
  float* ml     = ws + 67840;     // 2*131072
  // total ~1.32 MB

  hipMemsetAsync(ws, 0, 66561 * sizeof(float), stream);   // counts + dw + sq
  k_enorm<<<4, 256, 0, stream>>>(emb, enorm2);
  k_main<<<NROWS / 64, 256, 0, stream>>>(x, emb, temp, enorm2, ml, counts, sq, out);
  k_dw<<<512, 256, 0, stream>>>(x, emb, temp, enorm2, ml, dw);
  k_final<<<1, 256, 0, stream>>>(counts, dw, sq, ema_cs, ema_w, usage, out);
}

// Round 2
// 666.612 us; speedup vs baseline: 2.5068x; 2.5068x over previous
//
#include <hip/hip_runtime.h>
#include <stdint.h>

#define NROWS 131072          // 32*64*64 flattened rows
#define NELEM 8388608         // NROWS * 64

typedef __attribute__((ext_vector_type(8))) short bf16x8;
typedef __attribute__((ext_vector_type(4))) float f32x4;

// ---- bf16 split helpers (RNE) ----
__device__ __forceinline__ unsigned f2bf(float f) {
  unsigned u = __float_as_uint(f);
  u += 0x7fffu + ((u >> 16) & 1u);
  return u >> 16;
}
__device__ __forceinline__ float bf2f(unsigned short h) {
  return __uint_as_float(((unsigned)h) << 16);
}
__device__ __forceinline__ void split2(float f, unsigned short& hi, unsigned short& lo) {
  unsigned uh = f2bf(f);
  hi = (unsigned short)uh;
  lo = (unsigned short)f2bf(f - __uint_as_float(uh << 16));
}
__device__ __forceinline__ void pack8(const float* v, bf16x8& h8, bf16x8& l8) {
  #pragma unroll
  for (int i = 0; i < 8; ++i) {
    unsigned uh = f2bf(v[i]);
    float fh = __uint_as_float(uh << 16);
    unsigned ul = f2bf(v[i] - fh);
    h8[i] = (short)uh; l8[i] = (short)ul;
  }
}

// Row-major [*][64] bf16 matrix, 128B rows, XOR swizzle to kill b128 conflicts.
__device__ __forceinline__ int swz(int row, int bcol) {
  return row * 128 + (bcol ^ ((row & 7) << 4));
}

// bf16x3 fused product: D += (ah+al)*(bh+bl) dropping lo*lo (~2^-17 rel)
__device__ __forceinline__ f32x4 mfma3(bf16x8 ah, bf16x8 al, bf16x8 bh, bf16x8 bl, f32x4 c) {
  c = __builtin_amdgcn_mfma_f32_16x16x32_bf16(al, bh, c, 0, 0, 0);
  c = __builtin_amdgcn_mfma_f32_16x16x32_bf16(ah, bl, c, 0, 0, 0);
  c = __builtin_amdgcn_mfma_f32_16x16x32_bf16(ah, bh, c, 0, 0, 0);
  return c;
}

// ---------------- prep: emb -> bf16 hi/lo images (row-major + transposed),
// stored as the exact swizzled LDS byte-image per 64-code chunk; + ||e||^2/T ----
__global__ void prep_emb(const float* __restrict__ emb, const float* __restrict__ temp,
                         unsigned short* __restrict__ erh, unsigned short* __restrict__ erl,
                         unsigned short* __restrict__ eth, unsigned short* __restrict__ etl,
                         float* __restrict__ en2s)
{
  __shared__ float ef[64 * 64];
  const int c = blockIdx.x, t = threadIdx.x;
  const float4* g4 = (const float4*)(emb + (size_t)c * 4096);
  {
    int r = t >> 2, q0 = (t & 3) << 2;
    #pragma unroll
    for (int i = 0; i < 4; ++i) *(float4*)(ef + r * 64 + ((q0 + i) << 2)) = g4[r * 16 + q0 + i];
  }
  __syncthreads();
  char* ph = (char*)erh + c * 8192;  char* pl = (char*)erl + c * 8192;
  {
    int r = t >> 2, d0 = (t & 3) << 4;
    bf16x8 h8, l8;
    pack8(ef + r * 64 + d0, h8, l8);
    *(bf16x8*)(ph + swz(r, 2 * d0)) = h8;  *(bf16x8*)(pl + swz(r, 2 * d0)) = l8;
    pack8(ef + r * 64 + d0 + 8, h8, l8);
    *(bf16x8*)(ph + swz(r, 2 * d0 + 16)) = h8;  *(bf16x8*)(pl + swz(r, 2 * d0 + 16)) = l8;
  }
  char* qh = (char*)eth + c * 8192;  char* ql = (char*)etl + c * 8192;
  {
    int d = t >> 2, r0 = (t & 3) << 4;
    float tmp[16];
    #pragma unroll
    for (int i = 0; i < 16; ++i) tmp[i] = ef[(r0 + i) * 64 + d];
    bf16x8 h8, l8;
    pack8(tmp, h8, l8);
    *(bf16x8*)(qh + swz(d, 2 * r0)) = h8;  *(bf16x8*)(ql + swz(d, 2 * r0)) = l8;
    pack8(tmp + 8, h8, l8);
    *(bf16x8*)(qh + swz(d, 2 * r0 + 16)) = h8;  *(bf16x8*)(ql + swz(d, 2 * r0 + 16)) = l8;
  }
  if (t < 64) {
    float s = 0.f;
    #pragma unroll
    for (int j = 0; j < 64; ++j) { float v = ef[t * 64 + j]; s = fmaf(v, v, s); }
    en2s[c * 64 + t] = s / temp[0];
  }
}

// ---------------- kernel 1: stats + enc + quant + counts + sq (MFMA bf16x3) ----
__global__ __launch_bounds__(256, 2)
void k_main(const float* __restrict__ x, const float* __restrict__ temp,
            const unsigned short* __restrict__ erh, const unsigned short* __restrict__ erl,
            const unsigned short* __restrict__ eth, const unsigned short* __restrict__ etl,
            const float* __restrict__ en2s, float* __restrict__ b_g,
            float* __restrict__ counts_g, float* __restrict__ sq_g,
            float* __restrict__ out)
{
  __shared__ char EB[32768];   // ER hi @0, ER lo @8192, ET hi @16384, ET lo @24576
  __shared__ char XR[16384];   // x bf16 hi @0, lo @8192 (swizzled row-major)
  __shared__ char EN[16384];   // enc hi @0, lo @8192; first reused as fp32 x scratch
  __shared__ float cnt[1024];
  __shared__ float en2l[1024];

  const int tid = threadIdx.x;
  const int w = tid >> 6, lane = tid & 63, G = lane >> 4, ln = lane & 15;
  const int row_base = blockIdx.x << 6;
  const float invT = 1.0f / temp[0];
  const float c2 = 2.0f * invT;

  #pragma unroll
  for (int j = 0; j < 4; ++j) cnt[tid + (j << 8)] = 0.0f;
  ((float4*)en2l)[tid] = ((const float4*)en2s)[tid];

  // stage x fp32 into EN scratch
  float* xf = (float*)EN;
  {
    const float4* g4 = (const float4*)(x + (size_t)row_base * 64);
    #pragma unroll
    for (int j = 0; j < 4; ++j) ((float4*)xf)[tid + (j << 8)] = g4[tid + (j << 8)];
  }
  __syncthreads();
  // build XR hi/lo (swizzled)
  {
    int r = tid >> 2, d0 = (tid & 3) << 4;
    bf16x8 h8, l8;
    pack8(xf + r * 64 + d0, h8, l8);
    *(bf16x8*)(XR + swz(r, 2 * d0)) = h8;  *(bf16x8*)(XR + 8192 + swz(r, 2 * d0)) = l8;
    pack8(xf + r * 64 + d0 + 8, h8, l8);
    *(bf16x8*)(XR + swz(r, 2 * d0 + 16)) = h8;  *(bf16x8*)(XR + 8192 + swz(r, 2 * d0 + 16)) = l8;
  }
  __syncthreads();

  // resident A-frags: X rows 16w+ln, k = d
  bf16x8 axh[2], axl[2];
  #pragma unroll
  for (int kt = 0; kt < 2; ++kt) {
    axh[kt] = *(const bf16x8*)(XR + swz(16 * w + ln, 64 * kt + 16 * G));
    axl[kt] = *(const bf16x8*)(XR + 8192 + swz(16 * w + ln, 64 * kt + 16 * G));
  }

  float m[4], l[4];
  #pragma unroll
  for (int r = 0; r < 4; ++r) { m[r] = -3.0e38f; l[r] = 0.f; }

  // ---------- pass 1: online softmax stats ----------
  for (int c = 0; c < 16; ++c) {
    __syncthreads();
    {
      const uint4* sh = (const uint4*)((const char*)erh + c * 8192);
      const uint4* sl = (const uint4*)((const char*)erl + c * 8192);
      uint4* db = (uint4*)EB;
      db[tid] = sh[tid];           db[tid + 256] = sh[tid + 256];
      db[tid + 512] = sl[tid];     db[tid + 768] = sl[tid + 256];
    }
    __syncthreads();
    float s[4][4];
    #pragma unroll
    for (int nt = 0; nt < 4; ++nt) {
      f32x4 acc = {0.f, 0.f, 0.f, 0.f};
      #pragma unroll
      for (int kt = 0; kt < 2; ++kt) {
        bf16x8 bh = *(const bf16x8*)(EB + swz(16 * nt + ln, 64 * kt + 16 * G));
        bf16x8 bl = *(const bf16x8*)(EB + 8192 + swz(16 * nt + ln, 64 * kt + 16 * G));
        acc = mfma3(axh[kt], axl[kt], bh, bl, acc);
      }
      float e2 = en2l[(c << 6) + (nt << 4) + ln];
      #pragma unroll
      for (int r = 0; r < 4; ++r) s[nt][r] = acc[r] * c2 - e2;
    }
    #pragma unroll
    for (int r = 0; r < 4; ++r) {
      float cm = fmaxf(fmaxf(s[0][r], s[1][r]), fmaxf(s[2][r], s[3][r]));
      #pragma unroll
      for (int off = 1; off < 16; off <<= 1) cm = fmaxf(cm, __shfl_xor(cm, off, 16));
      float cl = __expf(s[0][r] - cm) + __expf(s[1][r] - cm) + __expf(s[2][r] - cm) + __expf(s[3][r] - cm);
      #pragma unroll
      for (int off = 1; off < 16; off <<= 1) cl += __shfl_xor(cl, off, 16);
      float mn = fmaxf(m[r], cm);
      l[r] = l[r] * __expf(m[r] - mn) + cl * __expf(cm - mn);
      m[r] = mn;
    }
  }

  float rl[4];
  #pragma unroll
  for (int r = 0; r < 4; ++r) rl[r] = 1.0f / l[r];
  if (ln == 0) {
    #pragma unroll
    for (int r = 0; r < 4; ++r)
      b_g[row_base + 16 * w + 4 * G + r] = m[r] + __logf(l[r]);
  }

  f32x4 qacc[4];
  #pragma unroll
  for (int nt = 0; nt < 4; ++nt) qacc[nt] = (f32x4){0.f, 0.f, 0.f, 0.f};

  // ---------- pass 2: enc -> quant / counts ----------
  for (int c = 0; c < 16; ++c) {
    __syncthreads();
    {
      const uint4* s0 = (const uint4*)((const char*)erh + c * 8192);
      const uint4* s1 = (const uint4*)((const char*)erl + c * 8192);
      const uint4* s2 = (const uint4*)((const char*)eth + c * 8192);
      const uint4* s3 = (const uint4*)((const char*)etl + c * 8192);
      uint4* db = (uint4*)EB;
      db[tid] = s0[tid];            db[tid + 256]  = s0[tid + 256];
      db[tid + 512] = s1[tid];      db[tid + 768]  = s1[tid + 256];
      db[tid + 1024] = s2[tid];     db[tid + 1280] = s2[tid + 256];
      db[tid + 1536] = s3[tid];     db[tid + 1792] = s3[tid + 256];
    }
    __syncthreads();
    float ev[4][4];
    #pragma unroll
    for (int nt = 0; nt < 4; ++nt) {
      f32x4 acc = {0.f, 0.f, 0.f, 0.f};
      #pragma unroll
      for (int kt = 0; kt < 2; ++kt) {
        bf16x8 bh = *(const bf16x8*)(EB + swz(16 * nt + ln, 64 * kt + 16 * G));
        bf16x8 bl = *(const bf16x8*)(EB + 8192 + swz(16 * nt + ln, 64 * kt + 16 * G));
        acc = mfma3(axh[kt], axl[kt], bh, bl, acc);
      }
      float e2 = en2l[(c << 6) + (nt << 4) + ln];
      #pragma unroll
      for (int r = 0; r < 4; ++r)
        ev[nt][r] = __expf(acc[r] * c2 - e2 - m[r]) * rl[r];
    }
    // counts (column sums)
    #pragma unroll
    for (int nt = 0; nt < 4; ++nt) {
      float v = ev[nt][0] + ev[nt][1] + ev[nt][2] + ev[nt][3];
      v += __shfl_xor(v, 16, 64);
      v += __shfl_xor(v, 32, 64);
      if (G == 0) atomicAdd(&cnt[(c << 6) + (nt << 4) + ln], v);
    }
    // write enc hi/lo (row-major swizzled)
    #pragma unroll
    for (int nt = 0; nt < 4; ++nt) {
      #pragma unroll
      for (int r = 0; r < 4; ++r) {
        int row = 16 * w + 4 * G + r, col = 16 * nt + ln;
        unsigned short h, lo;
        split2(ev[nt][r], h, lo);
        *(unsigned short*)(EN + swz(row, 2 * col)) = h;
        *(unsigned short*)(EN + 8192 + swz(row, 2 * col)) = lo;
      }
    }
    __syncthreads();
    // PV: quant^T = E^T * enc^T ; A = ET (d rows), B = enc row-major
    bf16x8 aeh[2], ael[2];
    #pragma unroll
    for (int kt = 0; kt < 2; ++kt) {
      aeh[kt] = *(const bf16x8*)(EB + 16384 + swz(16 * w + ln, 64 * kt + 16 * G));
      ael[kt] = *(const bf16x8*)(EB + 24576 + swz(16 * w + ln, 64 * kt + 16 * G));
    }
    #pragma unroll
    for (int nt = 0; nt < 4; ++nt) {
      #pragma unroll
      for (int kt = 0; kt < 2; ++kt) {
        bf16x8 bh = *(const bf16x8*)(EN + swz(16 * nt + ln, 64 * kt + 16 * G));
        bf16x8 bl = *(const bf16x8*)(EN + 8192 + swz(16 * nt + ln, 64 * kt + 16 * G));
        qacc[nt] = mfma3(aeh[kt], ael[kt], bh, bl, qacc[nt]);
      }
    }
  }

  // ---------- epilogue: write quant_st, accumulate sq ----------
  float sqp = 0.f;
  #pragma unroll
  for (int nt = 0; nt < 4; ++nt) {
    int orow = 16 * nt + ln;
    int d0 = 16 * w + 4 * G;
    int byte = swz(orow, 2 * d0);
    ushort4 xh = *(const ushort4*)(XR + byte);
    ushort4 xl = *(const ushort4*)(XR + 8192 + byte);
    float xv0 = bf2f(xh.x) + bf2f(xl.x), xv1 = bf2f(xh.y) + bf2f(xl.y);
    float xv2 = bf2f(xh.z) + bf2f(xl.z), xv3 = bf2f(xh.w) + bf2f(xl.w);
    float4 q = make_float4(qacc[nt][0], qacc[nt][1], qacc[nt][2], qacc[nt][3]);
    *(float4*)(out + (size_t)(row_base + orow) * 64 + d0) = q;
    float a = q.x - xv0, b = q.y - xv1, cdf = q.z - xv2, d = q.w - xv3;
    sqp += a * a + b * b + cdf * cdf + d * d;
  }
  #pragma unroll
  for (int off = 1; off < 64; off <<= 1) sqp += __shfl_xor(sqp, off, 64);
  if (lane == 0) atomicAdd(sq_g, sqp);

  __syncthreads();
  #pragma unroll
  for (int j = 0; j < 4; ++j) {
    int k = tid + (j << 8);
    atomicAdd(&counts_g[k], cnt[k]);
  }
}

// ---------------- kernel 2: dw = enc^T @ x (MFMA bf16x3, enc from stored b) ----
__global__ __launch_bounds__(256, 2)
void k_dw(const float* __restrict__ x, const float* __restrict__ temp,
          const unsigned short* __restrict__ erh, const unsigned short* __restrict__ erl,
          const float* __restrict__ en2s, const float* __restrict__ b_g,
          float* __restrict__ dw_g)
{
  __shared__ char ER[16384];    // 64 codes, hi @0 lo @8192
  __shared__ char XRb[16384];
  __shared__ char XTb[16384];
  __shared__ char ET2[16384];   // encT hi/lo; reused per chunk as fp32 x scratch
  __shared__ float bs[64];

  const int tid = threadIdx.x;
  const int w = tid >> 6, lane = tid & 63, G = lane >> 4, ln = lane & 15;
  const int kt_blk = blockIdx.x & 15;    // 16 ktiles x 64 codes
  const int rch = blockIdx.x >> 4;       // 64 row-chunks x 2048 rows
  const int kbase = kt_blk << 6;
  const float invT = 1.0f / temp[0];
  const float c2 = 2.0f * invT;

  {
    const uint4* sh = (const uint4*)((const char*)erh + kt_blk * 8192);
    const uint4* sl = (const uint4*)((const char*)erl + kt_blk * 8192);
    uint4* db = (uint4*)ER;
    db[tid] = sh[tid];        db[tid + 256] = sh[tid + 256];
    db[tid + 512] = sl[tid];  db[tid + 768] = sl[tid + 256];
  }
  const float en2v = en2s[kbase + 16 * w + ln];
  __syncthreads();
  bf16x8 beh[2], bel[2];   // static score B-frags: E codes 16w+ln
  #pragma unroll
  for (int kt = 0; kt < 2; ++kt) {
    beh[kt] = *(const bf16x8*)(ER + swz(16 * w + ln, 64 * kt + 16 * G));
    bel[kt] = *(const bf16x8*)(ER + 8192 + swz(16 * w + ln, 64 * kt + 16 * G));
  }

  f32x4 dwacc[4];
  #pragma unroll
  for (int nt = 0; nt < 4; ++nt) dwacc[nt] = (f32x4){0.f, 0.f, 0.f, 0.f};

  const int rows_base = rch << 11;
  for (int t = 0; t < 32; ++t) {
    const int rbase = rows_base + (t << 6);
    __syncthreads();   // ET2/XR/XT safe to overwrite
    float* xf = (float*)ET2;
    {
      const float4* g4 = (const float4*)(x + (size_t)rbase * 64);
      #pragma unroll
      for (int j = 0; j < 4; ++j) ((float4*)xf)[tid + (j << 8)] = g4[tid + (j << 8)];
    }
    if (tid < 64) bs[tid] = b_g[rbase + tid];
    __syncthreads();
    {
      int r = tid >> 2, d0 = (tid & 3) << 4;
      bf16x8 h8, l8;
      pack8(xf + r * 64 + d0, h8, l8);
      *(bf16x8*)(XRb + swz(r, 2 * d0)) = h8;  *(bf16x8*)(XRb + 8192 + swz(r, 2 * d0)) = l8;
      pack8(xf + r * 64 + d0 + 8, h8, l8);
      *(bf16x8*)(XRb + swz(r, 2 * d0 + 16)) = h8;  *(bf16x8*)(XRb + 8192 + swz(r, 2 * d0 + 16)) = l8;
      int d = tid >> 2, r0 = (tid & 3) << 4;
      float tmp[16];
      #pragma unroll
      for (int i = 0; i < 16; ++i) tmp[i] = xf[(r0 + i) * 64 + d];
      pack8(tmp, h8, l8);
      *(bf16x8*)(XTb + swz(d, 2 * r0)) = h8;  *(bf16x8*)(XTb + 8192 + swz(d, 2 * r0)) = l8;
      pack8(tmp + 8, h8, l8);
      *(bf16x8*)(XTb + swz(d, 2 * r0 + 16)) = h8;  *(bf16x8*)(XTb + 8192 + swz(d, 2 * r0 + 16)) = l8;
    }
    __syncthreads();   // XR/XT ready; xf no longer needed -> ET2 reusable for encT
    // score: rows 16rt+4G+r, code 16w+ln ; enc = exp(s - b_row)
    float ev[4][4];
    #pragma unroll
    for (int rt = 0; rt < 4; ++rt) {
      f32x4 acc = {0.f, 0.f, 0.f, 0.f};
      #pragma unroll
      for (int kt = 0; kt < 2; ++kt) {
        bf16x8 ah = *(const bf16x8*)(XRb + swz(16 * rt + ln, 64 * kt + 16 * G));
        bf16x8 al = *(const bf16x8*)(XRb + 8192 + swz(16 * rt + ln, 64 * kt + 16 * G));
        acc = mfma3(ah, al, beh[kt], bel[kt], acc);
      }
      #pragma unroll
      for (int r = 0; r < 4; ++r)
        ev[rt][r] = __expf(acc[r] * c2 - en2v - bs[16 * rt + 4 * G + r]);
    }
    // write encT (code-major) hi/lo
    #pragma unroll
    for (int rt = 0; rt < 4; ++rt) {
      int code = 16 * w + ln;
      int cb = 2 * (16 * rt + 4 * G);
      unsigned short h0, l0, h1, l1, h2, l2, h3, l3;
      split2(ev[rt][0], h0, l0); split2(ev[rt][1], h1, l1);
      split2(ev[rt][2], h2, l2); split2(ev[rt][3], h3, l3);
      ushort4 hv; hv.x = h0; hv.y = h1; hv.z = h2; hv.w = h3;
      ushort4 lv; lv.x = l0; lv.y = l1; lv.z = l2; lv.w = l3;
      *(ushort4*)(ET2 + swz(code, cb)) = hv;
      *(ushort4*)(ET2 + 8192 + swz(code, cb)) = lv;
    }
    __syncthreads();
    // dw: A = encT (codes 16w..), B = XT (d rows), k = orig rows
    bf16x8 aeh[2], ael[2];
    #pragma unroll
    for (int kt = 0; kt < 2; ++kt) {
      aeh[kt] = *(const bf16x8*)(ET2 + swz(16 * w + ln, 64 * kt + 16 * G));
      ael[kt] = *(const bf16x8*)(ET2 + 8192 + swz(16 * w + ln, 64 * kt + 16 * G));
    }
    #pragma unroll
    for (int nt = 0; nt < 4; ++nt) {
      #pragma unroll
      for (int kt = 0; kt < 2; ++kt) {
        bf16x8 bh = *(const bf16x8*)(XTb + swz(16 * nt + ln, 64 * kt + 16 * G));
        bf16x8 bl = *(const bf16x8*)(XTb + 8192 + swz(16 * nt + ln, 64 * kt + 16 * G));
        dwacc[nt] = mfma3(aeh[kt], ael[kt], bh, bl, dwacc[nt]);
      }
    }
  }
  #pragma unroll
  for (int nt = 0; nt < 4; ++nt) {
    #pragma unroll
    for (int r = 0; r < 4; ++r) {
      int code = kbase + 16 * w + 4 * G + r;
      int d = 16 * nt + ln;
      atomicAdd(&dw_g[code * 64 + d], dwacc[nt][r]);
    }
  }
}

// ---------------- kernel 3: finalize losses ----------------
__device__ __forceinline__ float blk_sum(float v, float* red4) {
  #pragma unroll
  for (int off = 1; off < 64; off <<= 1) v += __shfl_xor(v, off, 64);
  __syncthreads();
  if ((threadIdx.x & 63) == 0) red4[threadIdx.x >> 6] = v;
  __syncthreads();
  return red4[0] + red4[1] + red4[2] + red4[3];
}

__global__ void k_final(const float* __restrict__ counts_g, const float* __restrict__ dw_g,
                        const float* __restrict__ sq_g,
                        const float* __restrict__ ema_cs, const float* __restrict__ ema_w,
                        const float* __restrict__ usage, float* __restrict__ out)
{
  __shared__ float cs_lds[1024];
  __shared__ float red4[4];
  const int t = threadIdx.x;

  float4 c4 = ((const float4*)counts_g)[t];
  float4 e4 = ((const float4*)ema_cs)[t];
  float4 u4 = ((const float4*)usage)[t];
  float cntv[4] = {c4.x, c4.y, c4.z, c4.w};
  float ecs[4] = {e4.x, e4.y, e4.z, e4.w};
  float usg[4] = {u4.x, u4.y, u4.z, u4.w};

  float ncs[4], nu[4];
  float n_p = 0.f, snu_p = 0.f, ent_p = 0.f;
  #pragma unroll
  for (int j = 0; j < 4; ++j) {
    ncs[j] = fmaf(0.99f, ecs[j], 0.01f * cntv[j]);
    n_p += ncs[j];
    nu[j] = fmaf(0.99f, usg[j], 0.01f * cntv[j]);
    snu_p += nu[j];
    float avg = cntv[j] * (1.0f / 131072.0f);
    ent_p -= avg * logf(avg + 1e-10f);
  }
  float n = blk_sum(n_p, red4);
  float snu = blk_sum(snu_p, red4);
  float ent = blk_sum(ent_p, red4);

  float div_p = 0.f;
  float denom = n + 1024.0f * 1e-5f;
  #pragma unroll
  for (int j = 0; j < 4; ++j) {
    float cs = (ncs[j] + 1e-5f) / denom * n;
    cs_lds[(t << 2) + j] = cs;
    float up = nu[j] / (snu + 1e-5f);
    div_p -= up * logf(up + 1e-10f);
  }
  float dvr = blk_sum(div_p, red4);
  __syncthreads();

  float reg_p = 0.f;
  for (int j = 0; j < 256; ++j) {
    int i = t + (j << 8);
    float v = fmaf(0.01f, dw_g[i], 0.99f * ema_w[i]) / cs_lds[i >> 6];
    reg_p = fmaf(v, v, reg_p);
  }
  float reg = blk_sum(reg_p, red4);

  if (t == 0) {
    float mse = sq_g[0] * (1.0f / 8388608.0f);
    float loss = 1.25f * mse + reg + 0.8f * (ent + dvr);
    out[NELEM] = loss;
    out[NELEM + 1] = expf(ent);
  }
}

extern "C" void kernel_launch(void* const* d_in, const int* in_sizes, int n_in,
                              void* d_out, int out_size, void* d_ws, size_t ws_size,
                              hipStream_t stream)
{
  const float* x      = (const float*)d_in[0];
  const float* emb    = (const float*)d_in[1];
  const float* temp   = (const float*)d_in[2];
  const float* ema_cs = (const float*)d_in[3];
  const float* ema_w  = (const float*)d_in[4];
  const float* usage  = (const float*)d_in[5];
  float* out = (float*)d_out;
  float* ws  = (float*)d_ws;

  // workspace layout (floats)
  float* counts = ws;                              // 1024
  float* dwv    = ws + 1024;                       // 65536
  float* sq     = ws + 66560;                      // 1 (+pad)
  float* en2s   = ws + 66576;                      // 1024
  float* b_g    = ws + 67600;                      // 131072 (b = m + log l per row)
  unsigned short* erh = (unsigned short*)(ws + 198672);   // 128KB each image
  unsigned short* erl = (unsigned short*)(ws + 231440);
  unsigned short* eth = (unsigned short*)(ws + 264208);
  unsigned short* etl = (unsigned short*)(ws + 296976);
  // end: 329744 floats ~ 1.32 MB

  hipMemsetAsync(ws, 0, 66561 * sizeof(float), stream);  // counts + dw + sq
  prep_emb<<<16, 256, 0, stream>>>(emb, temp, erh, erl, eth, etl, en2s);
  k_main<<<NROWS / 64, 256, 0, stream>>>(x, temp, erh, erl, eth, etl, en2s, b_g, counts, sq, out);
  k_dw<<<1024, 256, 0, stream>>>(x, temp, erh, erl, en2s, b_g, dwv);
  k_final<<<1, 256, 0, stream>>>(counts, dwv, sq, ema_cs, ema_w, usage, out);
}

// Round 9
// 524.986 us; speedup vs baseline: 3.1831x; 1.2698x over previous
//
#include <hip/hip_runtime.h>
#include <stdint.h>

#define NROWS 131072
#define NELEM 8388608

typedef __attribute__((ext_vector_type(8))) short bf16x8;
typedef __attribute__((ext_vector_type(4))) float f32x4;

// ---- bf16 split helpers (RNE) ----
__device__ __forceinline__ unsigned f2bf(float f) {
  unsigned u = __float_as_uint(f);
  u += 0x7fffu + ((u >> 16) & 1u);
  return u >> 16;
}
__device__ __forceinline__ void split2(float f, unsigned short& hi, unsigned short& lo) {
  unsigned uh = f2bf(f);
  hi = (unsigned short)uh;
  lo = (unsigned short)f2bf(f - __uint_as_float(uh << 16));
}
__device__ __forceinline__ void pack8(const float* v, bf16x8& h8, bf16x8& l8) {
  #pragma unroll
  for (int i = 0; i < 8; ++i) {
    unsigned uh = f2bf(v[i]);
    unsigned ul = f2bf(v[i] - __uint_as_float(uh << 16));
    h8[i] = (short)uh; l8[i] = (short)ul;
  }
}
// Row-major [*][64] bf16 image, 128B rows, XOR swizzle (16B chunk granularity)
__device__ __forceinline__ int swz(int row, int bcol) {
  return row * 128 + (bcol ^ ((row & 7) << 4));
}
// bf16x3: D += (ah+al)*(bh+bl) dropping lo*lo
__device__ __forceinline__ f32x4 mfma3(bf16x8 ah, bf16x8 al, bf16x8 bh, bf16x8 bl, f32x4 c) {
  c = __builtin_amdgcn_mfma_f32_16x16x32_bf16(al, bh, c, 0, 0, 0);
  c = __builtin_amdgcn_mfma_f32_16x16x32_bf16(ah, bl, c, 0, 0, 0);
  c = __builtin_amdgcn_mfma_f32_16x16x32_bf16(ah, bh, c, 0, 0, 0);
  return c;
}
// async global->LDS, 16B per lane, linear
__device__ __forceinline__ void gl16(const void* g, void* l) {
  __builtin_amdgcn_global_load_lds((const __attribute__((address_space(1))) void*)g,
                                   (__attribute__((address_space(3))) void*)l, 16, 0, 0);
}

// ---------------- prep: emb -> swizzled bf16 hi/lo images (row + transposed), ||e||^2/T ----
__global__ void prep_emb(const float* __restrict__ emb, const float* __restrict__ temp,
                         char* __restrict__ erh, char* __restrict__ erl,
                         char* __restrict__ eth, char* __restrict__ etl,
                         float* __restrict__ en2s)
{
  __shared__ __align__(16) float ef[64 * 64];
  const int c = blockIdx.x, t = threadIdx.x;
  const float4* g4 = (const float4*)(emb + (size_t)c * 4096);
  {
    int r = t >> 2, q0 = (t & 3) << 2;
    #pragma unroll
    for (int i = 0; i < 4; ++i) *(float4*)(ef + r * 64 + ((q0 + i) << 2)) = g4[r * 16 + q0 + i];
  }
  __syncthreads();
  char* ph = erh + c * 8192;  char* pl = erl + c * 8192;
  {
    int r = t >> 2, d0 = (t & 3) << 4;
    bf16x8 h8, l8;
    pack8(ef + r * 64 + d0, h8, l8);
    *(bf16x8*)(ph + swz(r, 2 * d0)) = h8;  *(bf16x8*)(pl + swz(r, 2 * d0)) = l8;
    pack8(ef + r * 64 + d0 + 8, h8, l8);
    *(bf16x8*)(ph + swz(r, 2 * d0 + 16)) = h8;  *(bf16x8*)(pl + swz(r, 2 * d0 + 16)) = l8;
  }
  char* qh = eth + c * 8192;  char* ql = etl + c * 8192;
  {
    int d = t >> 2, r0 = (t & 3) << 4;
    float tmp[16];
    #pragma unroll
    for (int i = 0; i < 16; ++i) tmp[i] = ef[(r0 + i) * 64 + d];
    bf16x8 h8, l8;
    pack8(tmp, h8, l8);
    *(bf16x8*)(qh + swz(d, 2 * r0)) = h8;  *(bf16x8*)(ql + swz(d, 2 * r0)) = l8;
    pack8(tmp + 8, h8, l8);
    *(bf16x8*)(qh + swz(d, 2 * r0 + 16)) = h8;  *(bf16x8*)(ql + swz(d, 2 * r0 + 16)) = l8;
  }
  if (t < 64) {
    float s = 0.f;
    #pragma unroll
    for (int j = 0; j < 64; ++j) { float v = ef[t * 64 + j]; s = fmaf(v, v, s); }
    en2s[c * 64 + t] = s / temp[0];
  }
}

// ---------------- kernel 1: fused flash-style stats+quant+sq ----------------
__global__ __launch_bounds__(256, 3)
void k_main(const float* __restrict__ x, const float* __restrict__ temp,
            const char* __restrict__ erh, const char* __restrict__ erl,
            const char* __restrict__ eth, const char* __restrict__ etl,
            const float* __restrict__ en2s, float* __restrict__ b_g,
            float* __restrict__ sq_g, float* __restrict__ out)
{
  __shared__ __align__(16) char EB[32768];   // ER hi@0 lo@8192, ET hi@16384 lo@24576
  __shared__ __align__(16) char EN[16384];   // p hi@0 lo@8192 ; pre-loop: x fp32 tile
  __shared__ __align__(16) float en2l[1024];
  __shared__ float fac_l[64];
  __shared__ float linv_l[64];

  const int tid = threadIdx.x;
  const int w = tid >> 6, lane = tid & 63, G = lane >> 4, ln = lane & 15;
  const int row_base = blockIdx.x << 6;
  const float c2 = 2.0f / temp[0];

  // stage x fp32 -> EN scratch (async), en2l
  {
    const char* gx = (const char*)(x + (size_t)row_base * 64);
    #pragma unroll
    for (int j = 0; j < 4; ++j) gl16(gx + tid * 16 + j * 4096, EN + tid * 16 + j * 4096);
  }
  ((float4*)en2l)[tid] = ((const float4*)en2s)[tid];
  __syncthreads();

  // resident A-frags from fp32 tile: row 16w+ln, k cols [32kt+8G, +8)
  bf16x8 axh[2], axl[2];
  {
    const float* xr = (const float*)EN + (16 * w + ln) * 64;
    float tv[8];
    #pragma unroll
    for (int kt = 0; kt < 2; ++kt) {
      #pragma unroll
      for (int i = 0; i < 8; ++i) tv[i] = xr[32 * kt + 8 * G + i];
      pack8(tv, axh[kt], axl[kt]);
    }
  }

  float m[4], lsum[4];
  #pragma unroll
  for (int r = 0; r < 4; ++r) { m[r] = -3.0e38f; lsum[r] = 0.f; }
  f32x4 qacc[4];
  #pragma unroll
  for (int nt = 0; nt < 4; ++nt) qacc[nt] = (f32x4){0.f, 0.f, 0.f, 0.f};

  for (int c = 0; c < 16; ++c) {
    __syncthreads();                 // prev PV done; EB/EN/fac free
    {
      const char* s0 = erh + c * 8192; const char* s1 = erl + c * 8192;
      const char* s2 = eth + c * 8192; const char* s3 = etl + c * 8192;
      gl16(s0 + tid * 16, EB + tid * 16);
      gl16(s0 + 4096 + tid * 16, EB + 4096 + tid * 16);
      gl16(s1 + tid * 16, EB + 8192 + tid * 16);
      gl16(s1 + 4096 + tid * 16, EB + 12288 + tid * 16);
      gl16(s2 + tid * 16, EB + 16384 + tid * 16);
      gl16(s2 + 4096 + tid * 16, EB + 20480 + tid * 16);
      gl16(s3 + tid * 16, EB + 24576 + tid * 16);
      gl16(s3 + 4096 + tid * 16, EB + 28672 + tid * 16);
    }
    __syncthreads();
    // score
    float s[4][4];
    #pragma unroll
    for (int nt = 0; nt < 4; ++nt) {
      f32x4 acc = {0.f, 0.f, 0.f, 0.f};
      #pragma unroll
      for (int kt = 0; kt < 2; ++kt) {
        bf16x8 bh = *(const bf16x8*)(EB + swz(16 * nt + ln, 64 * kt + 16 * G));
        bf16x8 bl = *(const bf16x8*)(EB + 8192 + swz(16 * nt + ln, 64 * kt + 16 * G));
        acc = mfma3(axh[kt], axl[kt], bh, bl, acc);
      }
      float e2 = en2l[(c << 6) + (nt << 4) + ln];
      #pragma unroll
      for (int r = 0; r < 4; ++r) s[nt][r] = fmaf(acc[r], c2, -e2);
    }
    // online softmax update; p = exp(s - m_new) kept in s[][]
    float fac[4];
    #pragma unroll
    for (int r = 0; r < 4; ++r) {
      float cm = fmaxf(fmaxf(s[0][r], s[1][r]), fmaxf(s[2][r], s[3][r]));
      #pragma unroll
      for (int off = 1; off < 16; off <<= 1) cm = fmaxf(cm, __shfl_xor(cm, off, 16));
      float mn = fmaxf(m[r], cm);
      fac[r] = __expf(m[r] - mn);
      float p0 = __expf(s[0][r] - mn), p1 = __expf(s[1][r] - mn);
      float p2 = __expf(s[2][r] - mn), p3 = __expf(s[3][r] - mn);
      s[0][r] = p0; s[1][r] = p1; s[2][r] = p2; s[3][r] = p3;
      float cl = p0 + p1 + p2 + p3;
      #pragma unroll
      for (int off = 1; off < 16; off <<= 1) cl += __shfl_xor(cl, off, 16);
      lsum[r] = lsum[r] * fac[r] + cl;
      m[r] = mn;
    }
    if (ln == 0) {
      #pragma unroll
      for (int r = 0; r < 4; ++r) fac_l[16 * w + 4 * G + r] = fac[r];
    }
    // write p hi/lo image
    #pragma unroll
    for (int nt = 0; nt < 4; ++nt) {
      #pragma unroll
      for (int r = 0; r < 4; ++r) {
        int row = 16 * w + 4 * G + r, col = 16 * nt + ln;
        unsigned short h, lo2;
        split2(s[nt][r], h, lo2);
        *(unsigned short*)(EN + swz(row, 2 * col)) = h;
        *(unsigned short*)(EN + 8192 + swz(row, 2 * col)) = lo2;
      }
    }
    __syncthreads();
    // PV with rescale: A = ET (d rows), B = p
    bf16x8 aeh[2], ael[2];
    #pragma unroll
    for (int kt = 0; kt < 2; ++kt) {
      aeh[kt] = *(const bf16x8*)(EB + 16384 + swz(16 * w + ln, 64 * kt + 16 * G));
      ael[kt] = *(const bf16x8*)(EB + 24576 + swz(16 * w + ln, 64 * kt + 16 * G));
    }
    #pragma unroll
    for (int nt = 0; nt < 4; ++nt) {
      float f = fac_l[16 * nt + ln];
      qacc[nt][0] *= f; qacc[nt][1] *= f; qacc[nt][2] *= f; qacc[nt][3] *= f;
      #pragma unroll
      for (int kt = 0; kt < 2; ++kt) {
        bf16x8 bh = *(const bf16x8*)(EN + swz(16 * nt + ln, 64 * kt + 16 * G));
        bf16x8 bl = *(const bf16x8*)(EN + 8192 + swz(16 * nt + ln, 64 * kt + 16 * G));
        qacc[nt] = mfma3(aeh[kt], ael[kt], bh, bl, qacc[nt]);
      }
    }
  }

  if (ln == 0) {
    #pragma unroll
    for (int r = 0; r < 4; ++r) {
      int row = 16 * w + 4 * G + r;
      linv_l[row] = 1.0f / lsum[r];
      b_g[row_base + row] = m[r] + __logf(lsum[r]);
    }
  }
  __syncthreads();
  // epilogue: normalize, write out, sq
  float sqp = 0.f;
  #pragma unroll
  for (int nt = 0; nt < 4; ++nt) {
    int row = 16 * nt + ln;
    float li = linv_l[row];
    int d0 = 16 * w + 4 * G;
    float4 x4 = *(const float4*)(x + (size_t)(row_base + row) * 64 + d0);
    float4 q;
    q.x = qacc[nt][0] * li; q.y = qacc[nt][1] * li;
    q.z = qacc[nt][2] * li; q.w = qacc[nt][3] * li;
    *(float4*)(out + (size_t)(row_base + row) * 64 + d0) = q;
    float a = q.x - x4.x, b = q.y - x4.y, cc = q.z - x4.z, d = q.w - x4.w;
    sqp += a * a + b * b + cc * cc + d * d;
  }
  #pragma unroll
  for (int off = 1; off < 64; off <<= 1) sqp += __shfl_xor(sqp, off, 64);
  if (lane == 0) atomicAdd(sq_g, sqp);
}

// ---------------- kernel 2: dw = enc^T @ x  (+ counts) ----------------
__global__ __launch_bounds__(256, 3)
void k_dw(const float* __restrict__ x, const float* __restrict__ temp,
          const char* __restrict__ erh, const char* __restrict__ erl,
          const float* __restrict__ en2s, const float* __restrict__ b_g,
          float* __restrict__ dw_g, float* __restrict__ counts_g)
{
  __shared__ __align__(16) float XF[64 * 68];   // fp32 x tile, padded stride 68
  __shared__ __align__(16) char XT[16384];      // transposed x image hi@0 lo@8192
  __shared__ __align__(16) char ET2[16384];     // encT hi@0 lo@8192 ; pre-loop: ER image
  __shared__ float bs[64];

  const int tid = threadIdx.x;
  const int w = tid >> 6, lane = tid & 63, G = lane >> 4, ln = lane & 15;
  const int kt_blk = blockIdx.x & 15;    // 16 ktiles x 64 codes
  const int rch = blockIdx.x >> 4;       // 64 row-chunks x 2048 rows
  const int kbase = kt_blk << 6;
  const float c2 = 2.0f / temp[0];

  // stage ER into ET2 (temp), build static B-frags
  {
    const char* sh = erh + kt_blk * 8192;
    const char* sl = erl + kt_blk * 8192;
    gl16(sh + tid * 16, ET2 + tid * 16);
    gl16(sh + 4096 + tid * 16, ET2 + 4096 + tid * 16);
    gl16(sl + tid * 16, ET2 + 8192 + tid * 16);
    gl16(sl + 4096 + tid * 16, ET2 + 12288 + tid * 16);
  }
  const float en2v = en2s[kbase + 16 * w + ln];
  __syncthreads();
  bf16x8 beh[2], bel[2];
  #pragma unroll
  for (int kt = 0; kt < 2; ++kt) {
    beh[kt] = *(const bf16x8*)(ET2 + swz(16 * w + ln, 64 * kt + 16 * G));
    bel[kt] = *(const bf16x8*)(ET2 + 8192 + swz(16 * w + ln, 64 * kt + 16 * G));
  }

  f32x4 dwacc[4];
  #pragma unroll
  for (int nt = 0; nt < 4; ++nt) dwacc[nt] = (f32x4){0.f, 0.f, 0.f, 0.f};
  float creg = 0.f;

  const int rows_base = rch << 11;
  for (int t = 0; t < 32; ++t) {
    const int rbase = rows_base + (t << 6);
    __syncthreads();                       // prev dw done; XF/XT/ET2 free
    {
      const float4* g4 = (const float4*)(x + (size_t)rbase * 64);
      #pragma unroll
      for (int j = 0; j < 4; ++j) {
        int g = tid + (j << 8);
        int row = g >> 4, q = g & 15;
        *(float4*)(XF + row * 68 + (q << 2)) = g4[g];
      }
    }
    if (tid < 64) bs[tid] = b_g[rbase + tid];
    __syncthreads();
    // build XT (transpose) : thread owns column d, rows r0..r0+15
    {
      int d = tid & 63, r0 = (tid >> 6) << 4;
      float tmp[16];
      #pragma unroll
      for (int i = 0; i < 16; ++i) tmp[i] = XF[(r0 + i) * 68 + d];
      bf16x8 h8, l8;
      pack8(tmp, h8, l8);
      *(bf16x8*)(XT + swz(d, 2 * r0)) = h8;  *(bf16x8*)(XT + 8192 + swz(d, 2 * r0)) = l8;
      pack8(tmp + 8, h8, l8);
      *(bf16x8*)(XT + swz(d, 2 * r0 + 16)) = h8;  *(bf16x8*)(XT + 8192 + swz(d, 2 * r0 + 16)) = l8;
    }
    // score + enc: A packed just-in-time from padded XF
    float ev[4][4];
    #pragma unroll
    for (int rt = 0; rt < 4; ++rt) {
      const float* xr = XF + (16 * rt + ln) * 68;
      f32x4 acc = {0.f, 0.f, 0.f, 0.f};
      #pragma unroll
      for (int kt = 0; kt < 2; ++kt) {
        float tv[8];
        #pragma unroll
        for (int i = 0; i < 8; ++i) tv[i] = xr[32 * kt + 8 * G + i];
        bf16x8 ah, al;
        pack8(tv, ah, al);
        acc = mfma3(ah, al, beh[kt], bel[kt], acc);
      }
      #pragma unroll
      for (int r = 0; r < 4; ++r) {
        ev[rt][r] = __expf(fmaf(acc[r], c2, -en2v) - bs[16 * rt + 4 * G + r]);
        creg += ev[rt][r];
      }
    }
    // write encT (code-major) hi/lo
    #pragma unroll
    for (int rt = 0; rt < 4; ++rt) {
      int code = 16 * w + ln;
      int cb = 2 * (16 * rt + 4 * G);
      unsigned short h0, l0, h1, l1, h2, l2, h3, l3;
      split2(ev[rt][0], h0, l0); split2(ev[rt][1], h1, l1);
      split2(ev[rt][2], h2, l2); split2(ev[rt][3], h3, l3);
      ushort4 hv; hv.x = h0; hv.y = h1; hv.z = h2; hv.w = h3;
      ushort4 lv; lv.x = l0; lv.y = l1; lv.z = l2; lv.w = l3;
      *(ushort4*)(ET2 + swz(code, cb)) = hv;
      *(ushort4*)(ET2 + 8192 + swz(code, cb)) = lv;
    }
    __syncthreads();
    // dw: A = encT, B = XT, contract over the 64 rows
    bf16x8 aeh[2], ael[2];
    #pragma unroll
    for (int kt = 0; kt < 2; ++kt) {
      aeh[kt] = *(const bf16x8*)(ET2 + swz(16 * w + ln, 64 * kt + 16 * G));
      ael[kt] = *(const bf16x8*)(ET2 + 8192 + swz(16 * w + ln, 64 * kt + 16 * G));
    }
    #pragma unroll
    for (int nt = 0; nt < 4; ++nt) {
      #pragma unroll
      for (int kt = 0; kt < 2; ++kt) {
        bf16x8 bh = *(const bf16x8*)(XT + swz(16 * nt + ln, 64 * kt + 16 * G));
        bf16x8 bl = *(const bf16x8*)(XT + 8192 + swz(16 * nt + ln, 64 * kt + 16 * G));
        dwacc[nt] = mfma3(aeh[kt], ael[kt], bh, bl, dwacc[nt]);
      }
    }
  }
  #pragma unroll
  for (int nt = 0; nt < 4; ++nt) {
    #pragma unroll
    for (int r = 0; r < 4; ++r) {
      int code = kbase + 16 * w + 4 * G + r;
      int d = 16 * nt + ln;
      atomicAdd(&dw_g[code * 64 + d], dwacc[nt][r]);
    }
  }
  // counts: sum over the 64 rows handled by (G groups)
  creg += __shfl_xor(creg, 16, 64);
  creg += __shfl_xor(creg, 32, 64);
  if (G == 0) atomicAdd(&counts_g[kbase + 16 * w + ln], creg);
}

// ---------------- finalize ----------------
__device__ __forceinline__ float blk_sum(float v, float* red4) {
  #pragma unroll
  for (int off = 1; off < 64; off <<= 1) v += __shfl_xor(v, off, 64);
  __syncthreads();
  if ((threadIdx.x & 63) == 0) red4[threadIdx.x >> 6] = v;
  __syncthreads();
  return red4[0] + red4[1] + red4[2] + red4[3];
}

__global__ void k_stats(const float* __restrict__ counts_g, const float* __restrict__ ema_cs,
                        const float* __restrict__ usage, float* __restrict__ cs_g,
                        float* __restrict__ scal)
{
  __shared__ float red4[4];
  const int t = threadIdx.x;
  float4 c4 = ((const float4*)counts_g)[t];
  float4 e4 = ((const float4*)ema_cs)[t];
  float4 u4 = ((const float4*)usage)[t];
  float cnt[4] = {c4.x, c4.y, c4.z, c4.w};
  float ecs[4] = {e4.x, e4.y, e4.z, e4.w};
  float usg[4] = {u4.x, u4.y, u4.z, u4.w};
  float ncs[4], nu[4];
  float n_p = 0.f, snu_p = 0.f, ent_p = 0.f;
  #pragma unroll
  for (int j = 0; j < 4; ++j) {
    ncs[j] = fmaf(0.99f, ecs[j], 0.01f * cnt[j]);
    n_p += ncs[j];
    nu[j] = fmaf(0.99f, usg[j], 0.01f * cnt[j]);
    snu_p += nu[j];
    float avg = cnt[j] * (1.0f / 131072.0f);
    ent_p -= avg * logf(avg + 1e-10f);
  }
  float n = blk_sum(n_p, red4);
  float snu = blk_sum(snu_p, red4);
  float ent = blk_sum(ent_p, red4);
  float div_p = 0.f;
  float denom = n + 1024.0f * 1e-5f;
  float4 cso;
  float* csa = (float*)&cso;
  #pragma unroll
  for (int j = 0; j < 4; ++j) {
    csa[j] = (ncs[j] + 1e-5f) / denom * n;
    float up = nu[j] / (snu + 1e-5f);
    div_p -= up * logf(up + 1e-10f);
  }
  ((float4*)cs_g)[t] = cso;
  float dvr = blk_sum(div_p, red4);
  if (t == 0) { scal[0] = ent; scal[1] = dvr; }
}

__global__ void k_reg(const float* __restrict__ dw_g, const float* __restrict__ ema_w,
                      const float* __restrict__ cs_g, float* __restrict__ reg_g)
{
  int i = (blockIdx.x * 256 + threadIdx.x) * 2;
  float2 d2 = *(const float2*)(dw_g + i);
  float2 w2 = *(const float2*)(ema_w + i);
  float cs = cs_g[i >> 6];
  float v0 = fmaf(0.01f, d2.x, 0.99f * w2.x) / cs;
  float v1 = fmaf(0.01f, d2.y, 0.99f * w2.y) / cs;
  float p = v0 * v0 + v1 * v1;
  #pragma unroll
  for (int off = 1; off < 64; off <<= 1) p += __shfl_xor(p, off, 64);
  if ((threadIdx.x & 63) == 0) atomicAdd(reg_g, p);
}

__global__ void k_out(const float* __restrict__ sq_g, const float* __restrict__ reg_g,
                      const float* __restrict__ scal, float* __restrict__ out)
{
  if (threadIdx.x == 0) {
    float mse = sq_g[0] * (1.0f / 8388608.0f);
    float loss = 1.25f * mse + reg_g[0] + 0.8f * (scal[0] + scal[1]);
    out[NELEM] = loss;
    out[NELEM + 1] = expf(scal[0]);
  }
}

extern "C" void kernel_launch(void* const* d_in, const int* in_sizes, int n_in,
                              void* d_out, int out_size, void* d_ws, size_t ws_size,
                              hipStream_t stream)
{
  const float* x      = (const float*)d_in[0];
  const float* emb    = (const float*)d_in[1];
  const float* temp   = (const float*)d_in[2];
  const float* ema_cs = (const float*)d_in[3];
  const float* ema_w  = (const float*)d_in[4];
  const float* usage  = (const float*)d_in[5];
  float* out = (float*)d_out;
  float* ws  = (float*)d_ws;

  // workspace layout (floats)
  float* counts = ws;               // 1024
  float* dwv    = ws + 1024;        // 65536
  float* sq     = ws + 66560;       // 1
  float* reg    = ws + 66561;       // 1
  float* scal   = ws + 66562;       // 2 (ent, dvr)
  float* cs_g   = ws + 66576;       // 1024
  float* en2s   = ws + 67600;       // 1024
  float* b_g    = ws + 68624;       // 131072
  char* erh = (char*)(ws + 199696); // 128 KB each image
  char* erl = (char*)(ws + 232464);
  char* eth = (char*)(ws + 265232);
  char* etl = (char*)(ws + 298000);
  // end: 330768 floats ~ 1.32 MB

  hipMemsetAsync(ws, 0, 66564 * sizeof(float), stream);  // counts+dw+sq+reg+scal
  prep_emb<<<16, 256, 0, stream>>>(emb, temp, erh, erl, eth, etl, en2s);
  k_main<<<NROWS / 64, 256, 0, stream>>>(x, temp, erh, erl, eth, etl, en2s, b_g, sq, out);
  k_dw<<<1024, 256, 0, stream>>>(x, temp, erh, erl, en2s, b_g, dwv, counts);
  k_stats<<<1, 256, 0, stream>>>(counts, ema_cs, usage, cs_g, scal);
  k_reg<<<128, 256, 0, stream>>>(dwv, ema_w, cs_g, reg);
  k_out<<<1, 64, 0, stream>>>(sq, reg, scal, out);
}

// Round 10
// 455.269 us; speedup vs baseline: 3.6705x; 1.1531x over previous
//
#include <hip/hip_runtime.h>
#include <stdint.h>

#define NROWS 131072
#define NELEM 8388608

typedef __attribute__((ext_vector_type(8))) short bf16x8;
typedef __attribute__((ext_vector_type(4))) float f32x4;

// ---- bf16 split helpers (RNE) ----
__device__ __forceinline__ unsigned f2bf(float f) {
  unsigned u = __float_as_uint(f);
  u += 0x7fffu + ((u >> 16) & 1u);
  return u >> 16;
}
__device__ __forceinline__ void split2(float f, unsigned short& hi, unsigned short& lo) {
  unsigned uh = f2bf(f);
  hi = (unsigned short)uh;
  lo = (unsigned short)f2bf(f - __uint_as_float(uh << 16));
}
__device__ __forceinline__ void pack8(const float* v, bf16x8& h8, bf16x8& l8) {
  #pragma unroll
  for (int i = 0; i < 8; ++i) {
    unsigned uh = f2bf(v[i]);
    unsigned ul = f2bf(v[i] - __uint_as_float(uh << 16));
    h8[i] = (short)uh; l8[i] = (short)ul;
  }
}
// Row-major [*][64] bf16 image, 128B rows, XOR swizzle (16B chunk granularity)
__device__ __forceinline__ int swz(int row, int bcol) {
  return row * 128 + (bcol ^ ((row & 7) << 4));
}
// bf16x3: D += (ah+al)*(bh+bl) dropping lo*lo
__device__ __forceinline__ f32x4 mfma3(bf16x8 ah, bf16x8 al, bf16x8 bh, bf16x8 bl, f32x4 c) {
  c = __builtin_amdgcn_mfma_f32_16x16x32_bf16(al, bh, c, 0, 0, 0);
  c = __builtin_amdgcn_mfma_f32_16x16x32_bf16(ah, bl, c, 0, 0, 0);
  c = __builtin_amdgcn_mfma_f32_16x16x32_bf16(ah, bh, c, 0, 0, 0);
  return c;
}
// async global->LDS, 16B per lane, linear
__device__ __forceinline__ void gl16(const void* g, void* l) {
  __builtin_amdgcn_global_load_lds((const __attribute__((address_space(1))) void*)g,
                                   (__attribute__((address_space(3))) void*)l, 16, 0, 0);
}

// Build row-major + transposed swizzled bf16 hi/lo images of one 64x64 fp32 tile.
__device__ __forceinline__ void build_images(const float* __restrict__ src,
                                             char* __restrict__ rh, char* __restrict__ rl,
                                             char* __restrict__ th, char* __restrict__ tl,
                                             float* ef, int t)
{
  const float4* g4 = (const float4*)src;
  {
    int r = t >> 2, q0 = (t & 3) << 2;
    #pragma unroll
    for (int i = 0; i < 4; ++i) *(float4*)(ef + r * 64 + ((q0 + i) << 2)) = g4[r * 16 + q0 + i];
  }
  __syncthreads();
  {
    int r = t >> 2, d0 = (t & 3) << 4;
    bf16x8 h8, l8;
    pack8(ef + r * 64 + d0, h8, l8);
    *(bf16x8*)(rh + swz(r, 2 * d0)) = h8;  *(bf16x8*)(rl + swz(r, 2 * d0)) = l8;
    pack8(ef + r * 64 + d0 + 8, h8, l8);
    *(bf16x8*)(rh + swz(r, 2 * d0 + 16)) = h8;  *(bf16x8*)(rl + swz(r, 2 * d0 + 16)) = l8;
  }
  {
    int d = t >> 2, r0 = (t & 3) << 4;
    float tmp[16];
    #pragma unroll
    for (int i = 0; i < 16; ++i) tmp[i] = ef[(r0 + i) * 64 + d];
    bf16x8 h8, l8;
    pack8(tmp, h8, l8);
    *(bf16x8*)(th + swz(d, 2 * r0)) = h8;  *(bf16x8*)(tl + swz(d, 2 * r0)) = l8;
    pack8(tmp + 8, h8, l8);
    *(bf16x8*)(th + swz(d, 2 * r0 + 16)) = h8;  *(bf16x8*)(tl + swz(d, 2 * r0 + 16)) = l8;
  }
}

// ---------------- prep: emb -> images + ||e||^2/T ----------------
__global__ void prep_emb(const float* __restrict__ emb, const float* __restrict__ temp,
                         char* __restrict__ erh, char* __restrict__ erl,
                         char* __restrict__ eth, char* __restrict__ etl,
                         float* __restrict__ en2s)
{
  __shared__ __align__(16) float ef[64 * 64];
  const int c = blockIdx.x, t = threadIdx.x;
  build_images(emb + (size_t)c * 4096, erh + c * 8192, erl + c * 8192,
               eth + c * 8192, etl + c * 8192, ef, t);
  if (t < 64) {
    float s = 0.f;
    #pragma unroll
    for (int j = 0; j < 64; ++j) { float v = ef[t * 64 + j]; s = fmaf(v, v, s); }
    en2s[c * 64 + t] = s / temp[0];
  }
}

// ---------------- prep: x -> images (fast path only) ----------------
__global__ void prep_x(const float* __restrict__ x,
                       char* __restrict__ xrh, char* __restrict__ xrl,
                       char* __restrict__ xth, char* __restrict__ xtl)
{
  __shared__ __align__(16) float ef[64 * 64];
  const int c = blockIdx.x, t = threadIdx.x;
  build_images(x + (size_t)c * 4096, xrh + (size_t)c * 8192, xrl + (size_t)c * 8192,
               xth + (size_t)c * 8192, xtl + (size_t)c * 8192, ef, t);
}

// ---------------- kernel 1: fused flash-style stats+quant+sq ----------------
__global__ __launch_bounds__(256, 3)
void k_main(const float* __restrict__ x, const float* __restrict__ temp,
            const char* __restrict__ erh, const char* __restrict__ erl,
            const char* __restrict__ eth, const char* __restrict__ etl,
            const float* __restrict__ en2s, float* __restrict__ b_g,
            float* __restrict__ sq_g, float* __restrict__ out)
{
  __shared__ __align__(16) char EB[32768];   // ER hi@0 lo@8192, ET hi@16384 lo@24576
  __shared__ __align__(16) char EN[16384];   // p hi@0 lo@8192 ; pre-loop: x fp32 tile
  __shared__ __align__(16) float en2l[1024];
  __shared__ float fac_l[64];
  __shared__ float linv_l[64];

  const int tid = threadIdx.x;
  const int w = tid >> 6, lane = tid & 63, G = lane >> 4, ln = lane & 15;
  const int row_base = blockIdx.x << 6;
  const float c2 = 2.0f / temp[0];

  // stage x fp32 -> EN scratch (async), en2l
  {
    const char* gx = (const char*)(x + (size_t)row_base * 64);
    #pragma unroll
    for (int j = 0; j < 4; ++j) gl16(gx + tid * 16 + j * 4096, EN + tid * 16 + j * 4096);
  }
  ((float4*)en2l)[tid] = ((const float4*)en2s)[tid];
  __syncthreads();

  // resident A-frags from fp32 tile: row 16w+ln, k cols [32kt+8G, +8)
  bf16x8 axh[2], axl[2];
  {
    const float* xr = (const float*)EN + (16 * w + ln) * 64;
    float tv[8];
    #pragma unroll
    for (int kt = 0; kt < 2; ++kt) {
      #pragma unroll
      for (int i = 0; i < 8; ++i) tv[i] = xr[32 * kt + 8 * G + i];
      pack8(tv, axh[kt], axl[kt]);
    }
  }

  float m[4], lsum[4];
  #pragma unroll
  for (int r = 0; r < 4; ++r) { m[r] = -3.0e38f; lsum[r] = 0.f; }
  f32x4 qacc[4];
  #pragma unroll
  for (int nt = 0; nt < 4; ++nt) qacc[nt] = (f32x4){0.f, 0.f, 0.f, 0.f};

  for (int c = 0; c < 16; ++c) {
    __syncthreads();                 // prev PV done; EB/EN/fac free
    {
      const char* s0 = erh + c * 8192; const char* s1 = erl + c * 8192;
      const char* s2 = eth + c * 8192; const char* s3 = etl + c * 8192;
      gl16(s0 + tid * 16, EB + tid * 16);
      gl16(s0 + 4096 + tid * 16, EB + 4096 + tid * 16);
      gl16(s1 + tid * 16, EB + 8192 + tid * 16);
      gl16(s1 + 4096 + tid * 16, EB + 12288 + tid * 16);
      gl16(s2 + tid * 16, EB + 16384 + tid * 16);
      gl16(s2 + 4096 + tid * 16, EB + 20480 + tid * 16);
      gl16(s3 + tid * 16, EB + 24576 + tid * 16);
      gl16(s3 + 4096 + tid * 16, EB + 28672 + tid * 16);
    }
    __syncthreads();
    // score
    float s[4][4];
    #pragma unroll
    for (int nt = 0; nt < 4; ++nt) {
      f32x4 acc = {0.f, 0.f, 0.f, 0.f};
      #pragma unroll
      for (int kt = 0; kt < 2; ++kt) {
        bf16x8 bh = *(const bf16x8*)(EB + swz(16 * nt + ln, 64 * kt + 16 * G));
        bf16x8 bl = *(const bf16x8*)(EB + 8192 + swz(16 * nt + ln, 64 * kt + 16 * G));
        acc = mfma3(axh[kt], axl[kt], bh, bl, acc);
      }
      float e2 = en2l[(c << 6) + (nt << 4) + ln];
      #pragma unroll
      for (int r = 0; r < 4; ++r) s[nt][r] = fmaf(acc[r], c2, -e2);
    }
    // online softmax update; p = exp(s - m_new) kept in s[][]
    float fac[4];
    #pragma unroll
    for (int r = 0; r < 4; ++r) {
      float cm = fmaxf(fmaxf(s[0][r], s[1][r]), fmaxf(s[2][r], s[3][r]));
      #pragma unroll
      for (int off = 1; off < 16; off <<= 1) cm = fmaxf(cm, __shfl_xor(cm, off, 16));
      float mn = fmaxf(m[r], cm);
      fac[r] = __expf(m[r] - mn);
      float p0 = __expf(s[0][r] - mn), p1 = __expf(s[1][r] - mn);
      float p2 = __expf(s[2][r] - mn), p3 = __expf(s[3][r] - mn);
      s[0][r] = p0; s[1][r] = p1; s[2][r] = p2; s[3][r] = p3;
      float cl = p0 + p1 + p2 + p3;
      #pragma unroll
      for (int off = 1; off < 16; off <<= 1) cl += __shfl_xor(cl, off, 16);
      lsum[r] = lsum[r] * fac[r] + cl;
      m[r] = mn;
    }
    if (ln == 0) {
      #pragma unroll
      for (int r = 0; r < 4; ++r) fac_l[16 * w + 4 * G + r] = fac[r];
    }
    // write p hi/lo image
    #pragma unroll
    for (int nt = 0; nt < 4; ++nt) {
      #pragma unroll
      for (int r = 0; r < 4; ++r) {
        int row = 16 * w + 4 * G + r, col = 16 * nt + ln;
        unsigned short h, lo2;
        split2(s[nt][r], h, lo2);
        *(unsigned short*)(EN + swz(row, 2 * col)) = h;
        *(unsigned short*)(EN + 8192 + swz(row, 2 * col)) = lo2;
      }
    }
    __syncthreads();
    // PV with rescale: A = ET (d rows), B = p
    bf16x8 aeh[2], ael[2];
    #pragma unroll
    for (int kt = 0; kt < 2; ++kt) {
      aeh[kt] = *(const bf16x8*)(EB + 16384 + swz(16 * w + ln, 64 * kt + 16 * G));
      ael[kt] = *(const bf16x8*)(EB + 24576 + swz(16 * w + ln, 64 * kt + 16 * G));
    }
    #pragma unroll
    for (int nt = 0; nt < 4; ++nt) {
      float f = fac_l[16 * nt + ln];
      qacc[nt][0] *= f; qacc[nt][1] *= f; qacc[nt][2] *= f; qacc[nt][3] *= f;
      #pragma unroll
      for (int kt = 0; kt < 2; ++kt) {
        bf16x8 bh = *(const bf16x8*)(EN + swz(16 * nt + ln, 64 * kt + 16 * G));
        bf16x8 bl = *(const bf16x8*)(EN + 8192 + swz(16 * nt + ln, 64 * kt + 16 * G));
        qacc[nt] = mfma3(aeh[kt], ael[kt], bh, bl, qacc[nt]);
      }
    }
  }

  if (ln == 0) {
    #pragma unroll
    for (int r = 0; r < 4; ++r) {
      int row = 16 * w + 4 * G + r;
      linv_l[row] = 1.0f / lsum[r];
      b_g[row_base + row] = m[r] + __logf(lsum[r]);
    }
  }
  __syncthreads();
  // epilogue: normalize, write out, sq
  float sqp = 0.f;
  #pragma unroll
  for (int nt = 0; nt < 4; ++nt) {
    int row = 16 * nt + ln;
    float li = linv_l[row];
    int d0 = 16 * w + 4 * G;
    float4 x4 = *(const float4*)(x + (size_t)(row_base + row) * 64 + d0);
    float4 q;
    q.x = qacc[nt][0] * li; q.y = qacc[nt][1] * li;
    q.z = qacc[nt][2] * li; q.w = qacc[nt][3] * li;
    *(float4*)(out + (size_t)(row_base + row) * 64 + d0) = q;
    float a = q.x - x4.x, b = q.y - x4.y, cc = q.z - x4.z, d = q.w - x4.w;
    sqp += a * a + b * b + cc * cc + d * d;
  }
  #pragma unroll
  for (int off = 1; off < 64; off <<= 1) sqp += __shfl_xor(sqp, off, 64);
  if (lane == 0) atomicAdd(sq_g, sqp);
}

// ---------------- kernel 2 (fast): dw = enc^T @ x from precomputed x images ----------------
__global__ __launch_bounds__(256, 3)
void k_dw_fast(const float* __restrict__ temp,
               const char* __restrict__ erh, const char* __restrict__ erl,
               const char* __restrict__ xrh, const char* __restrict__ xrl,
               const char* __restrict__ xth, const char* __restrict__ xtl,
               const float* __restrict__ en2s, const float* __restrict__ b_g,
               float* __restrict__ dw_g, float* __restrict__ counts_g)
{
  __shared__ __align__(16) char XR[16384];   // x row image hi@0 lo@8192
  __shared__ __align__(16) char XT[16384];   // x transposed image hi@0 lo@8192
  __shared__ __align__(16) char ET2[16384];  // encT hi@0 lo@8192 ; pre-loop: ER image
  __shared__ float bs[64];

  const int tid = threadIdx.x;
  const int w = tid >> 6, lane = tid & 63, G = lane >> 4, ln = lane & 15;
  const int kt_blk = blockIdx.x & 15;    // 16 ktiles x 64 codes
  const int rch = blockIdx.x >> 4;       // 64 row-chunks x 2048 rows
  const int kbase = kt_blk << 6;
  const float c2 = 2.0f / temp[0];

  // stage ER into ET2 (temp), build static B-frags
  {
    const char* sh = erh + kt_blk * 8192;
    const char* sl = erl + kt_blk * 8192;
    gl16(sh + tid * 16, ET2 + tid * 16);
    gl16(sh + 4096 + tid * 16, ET2 + 4096 + tid * 16);
    gl16(sl + tid * 16, ET2 + 8192 + tid * 16);
    gl16(sl + 4096 + tid * 16, ET2 + 12288 + tid * 16);
  }
  const float en2v = en2s[kbase + 16 * w + ln];
  __syncthreads();
  bf16x8 beh[2], bel[2];
  #pragma unroll
  for (int kt = 0; kt < 2; ++kt) {
    beh[kt] = *(const bf16x8*)(ET2 + swz(16 * w + ln, 64 * kt + 16 * G));
    bel[kt] = *(const bf16x8*)(ET2 + 8192 + swz(16 * w + ln, 64 * kt + 16 * G));
  }

  f32x4 dwacc[4];
  #pragma unroll
  for (int nt = 0; nt < 4; ++nt) dwacc[nt] = (f32x4){0.f, 0.f, 0.f, 0.f};
  float creg = 0.f;

  const int tiles_base = rch << 5;       // 32 tiles of 64 rows
  for (int t = 0; t < 32; ++t) {
    const size_t ib = (size_t)(tiles_base + t) * 8192;
    const int rbase = (tiles_base + t) << 6;
    __syncthreads();                     // prev score/dw done reading XR/XT/ET2
    gl16(xrh + ib + tid * 16, XR + tid * 16);
    gl16(xrh + ib + 4096 + tid * 16, XR + 4096 + tid * 16);
    gl16(xrl + ib + tid * 16, XR + 8192 + tid * 16);
    gl16(xrl + ib + 4096 + tid * 16, XR + 12288 + tid * 16);
    gl16(xth + ib + tid * 16, XT + tid * 16);
    gl16(xth + ib + 4096 + tid * 16, XT + 4096 + tid * 16);
    gl16(xtl + ib + tid * 16, XT + 8192 + tid * 16);
    gl16(xtl + ib + 4096 + tid * 16, XT + 12288 + tid * 16);
    if (tid < 64) bs[tid] = b_g[rbase + tid];
    __syncthreads();
    // score: A = x rows (direct frag reads), B = E codes (static regs)
    float ev[4][4];
    #pragma unroll
    for (int rt = 0; rt < 4; ++rt) {
      f32x4 acc = {0.f, 0.f, 0.f, 0.f};
      #pragma unroll
      for (int kt = 0; kt < 2; ++kt) {
        bf16x8 ah = *(const bf16x8*)(XR + swz(16 * rt + ln, 64 * kt + 16 * G));
        bf16x8 al = *(const bf16x8*)(XR + 8192 + swz(16 * rt + ln, 64 * kt + 16 * G));
        acc = mfma3(ah, al, beh[kt], bel[kt], acc);
      }
      #pragma unroll
      for (int r = 0; r < 4; ++r) {
        ev[rt][r] = __expf(fmaf(acc[r], c2, -en2v) - bs[16 * rt + 4 * G + r]);
        creg += ev[rt][r];
      }
    }
    // write encT (code-major) hi/lo
    #pragma unroll
    for (int rt = 0; rt < 4; ++rt) {
      int code = 16 * w + ln;
      int cb = 2 * (16 * rt + 4 * G);
      unsigned short h0, l0, h1, l1, h2, l2, h3, l3;
      split2(ev[rt][0], h0, l0); split2(ev[rt][1], h1, l1);
      split2(ev[rt][2], h2, l2); split2(ev[rt][3], h3, l3);
      ushort4 hv; hv.x = h0; hv.y = h1; hv.z = h2; hv.w = h3;
      ushort4 lv; lv.x = l0; lv.y = l1; lv.z = l2; lv.w = l3;
      *(ushort4*)(ET2 + swz(code, cb)) = hv;
      *(ushort4*)(ET2 + 8192 + swz(code, cb)) = lv;
    }
    __syncthreads();
    // dw: A = encT, B = XT (direct frag reads), contract over the 64 rows
    bf16x8 aeh[2], ael[2];
    #pragma unroll
    for (int kt = 0; kt < 2; ++kt) {
      aeh[kt] = *(const bf16x8*)(ET2 + swz(16 * w + ln, 64 * kt + 16 * G));
      ael[kt] = *(const bf16x8*)(ET2 + 8192 + swz(16 * w + ln, 64 * kt + 16 * G));
    }
    #pragma unroll
    for (int nt = 0; nt < 4; ++nt) {
      #pragma unroll
      for (int kt = 0; kt < 2; ++kt) {
        bf16x8 bh = *(const bf16x8*)(XT + swz(16 * nt + ln, 64 * kt + 16 * G));
        bf16x8 bl = *(const bf16x8*)(XT + 8192 + swz(16 * nt + ln, 64 * kt + 16 * G));
        dwacc[nt] = mfma3(aeh[kt], ael[kt], bh, bl, dwacc[nt]);
      }
    }
  }
  #pragma unroll
  for (int nt = 0; nt < 4; ++nt) {
    #pragma unroll
    for (int r = 0; r < 4; ++r) {
      int code = kbase + 16 * w + 4 * G + r;
      int d = 16 * nt + ln;
      atomicAdd(&dw_g[code * 64 + d], dwacc[nt][r]);
    }
  }
  creg += __shfl_xor(creg, 16, 64);
  creg += __shfl_xor(creg, 32, 64);
  if (G == 0) atomicAdd(&counts_g[kbase + 16 * w + ln], creg);
}

// ---------------- kernel 2 (fallback, R9-measured): dw with in-kernel packing ----------------
__global__ __launch_bounds__(256, 3)
void k_dw(const float* __restrict__ x, const float* __restrict__ temp,
          const char* __restrict__ erh, const char* __restrict__ erl,
          const float* __restrict__ en2s, const float* __restrict__ b_g,
          float* __restrict__ dw_g, float* __restrict__ counts_g)
{
  __shared__ __align__(16) float XF[64 * 68];
  __shared__ __align__(16) char XT[16384];
  __shared__ __align__(16) char ET2[16384];
  __shared__ float bs[64];

  const int tid = threadIdx.x;
  const int w = tid >> 6, lane = tid & 63, G = lane >> 4, ln = lane & 15;
  const int kt_blk = blockIdx.x & 15;
  const int rch = blockIdx.x >> 4;
  const int kbase = kt_blk << 6;
  const float c2 = 2.0f / temp[0];

  {
    const char* sh = erh + kt_blk * 8192;
    const char* sl = erl + kt_blk * 8192;
    gl16(sh + tid * 16, ET2 + tid * 16);
    gl16(sh + 4096 + tid * 16, ET2 + 4096 + tid * 16);
    gl16(sl + tid * 16, ET2 + 8192 + tid * 16);
    gl16(sl + 4096 + tid * 16, ET2 + 12288 + tid * 16);
  }
  const float en2v = en2s[kbase + 16 * w + ln];
  __syncthreads();
  bf16x8 beh[2], bel[2];
  #pragma unroll
  for (int kt = 0; kt < 2; ++kt) {
    beh[kt] = *(const bf16x8*)(ET2 + swz(16 * w + ln, 64 * kt + 16 * G));
    bel[kt] = *(const bf16x8*)(ET2 + 8192 + swz(16 * w + ln, 64 * kt + 16 * G));
  }

  f32x4 dwacc[4];
  #pragma unroll
  for (int nt = 0; nt < 4; ++nt) dwacc[nt] = (f32x4){0.f, 0.f, 0.f, 0.f};
  float creg = 0.f;

  const int rows_base = rch << 11;
  for (int t = 0; t < 32; ++t) {
    const int rbase = rows_base + (t << 6);
    __syncthreads();
    {
      const float4* g4 = (const float4*)(x + (size_t)rbase * 64);
      #pragma unroll
      for (int j = 0; j < 4; ++j) {
        int g = tid + (j << 8);
        int row = g >> 4, q = g & 15;
        *(float4*)(XF + row * 68 + (q << 2)) = g4[g];
      }
    }
    if (tid < 64) bs[tid] = b_g[rbase + tid];
    __syncthreads();
    {
      int d = tid & 63, r0 = (tid >> 6) << 4;
      float tmp[16];
      #pragma unroll
      for (int i = 0; i < 16; ++i) tmp[i] = XF[(r0 + i) * 68 + d];
      bf16x8 h8, l8;
      pack8(tmp, h8, l8);
      *(bf16x8*)(XT + swz(d, 2 * r0)) = h8;  *(bf16x8*)(XT + 8192 + swz(d, 2 * r0)) = l8;
      pack8(tmp + 8, h8, l8);
      *(bf16x8*)(XT + swz(d, 2 * r0 + 16)) = h8;  *(bf16x8*)(XT + 8192 + swz(d, 2 * r0 + 16)) = l8;
    }
    float ev[4][4];
    #pragma unroll
    for (int rt = 0; rt < 4; ++rt) {
      const float* xr = XF + (16 * rt + ln) * 68;
      f32x4 acc = {0.f, 0.f, 0.f, 0.f};
      #pragma unroll
      for (int kt = 0; kt < 2; ++kt) {
        float tv[8];
        #pragma unroll
        for (int i = 0; i < 8; ++i) tv[i] = xr[32 * kt + 8 * G + i];
        bf16x8 ah, al;
        pack8(tv, ah, al);
        acc = mfma3(ah, al, beh[kt], bel[kt], acc);
      }
      #pragma unroll
      for (int r = 0; r < 4; ++r) {
        ev[rt][r] = __expf(fmaf(acc[r], c2, -en2v) - bs[16 * rt + 4 * G + r]);
        creg += ev[rt][r];
      }
    }
    #pragma unroll
    for (int rt = 0; rt < 4; ++rt) {
      int code = 16 * w + ln;
      int cb = 2 * (16 * rt + 4 * G);
      unsigned short h0, l0, h1, l1, h2, l2, h3, l3;
      split2(ev[rt][0], h0, l0); split2(ev[rt][1], h1, l1);
      split2(ev[rt][2], h2, l2); split2(ev[rt][3], h3, l3);
      ushort4 hv; hv.x = h0; hv.y = h1; hv.z = h2; hv.w = h3;
      ushort4 lv; lv.x = l0; lv.y = l1; lv.z = l2; lv.w = l3;
      *(ushort4*)(ET2 + swz(code, cb)) = hv;
      *(ushort4*)(ET2 + 8192 + swz(code, cb)) = lv;
    }
    __syncthreads();
    bf16x8 aeh[2], ael[2];
    #pragma unroll
    for (int kt = 0; kt < 2; ++kt) {
      aeh[kt] = *(const bf16x8*)(ET2 + swz(16 * w + ln, 64 * kt + 16 * G));
      ael[kt] = *(const bf16x8*)(ET2 + 8192 + swz(16 * w + ln, 64 * kt + 16 * G));
    }
    #pragma unroll
    for (int nt = 0; nt < 4; ++nt) {
      #pragma unroll
      for (int kt = 0; kt < 2; ++kt) {
        bf16x8 bh = *(const bf16x8*)(XT + swz(16 * nt + ln, 64 * kt + 16 * G));
        bf16x8 bl = *(const bf16x8*)(XT + 8192 + swz(16 * nt + ln, 64 * kt + 16 * G));
        dwacc[nt] = mfma3(aeh[kt], ael[kt], bh, bl, dwacc[nt]);
      }
    }
  }
  #pragma unroll
  for (int nt = 0; nt < 4; ++nt) {
    #pragma unroll
    for (int r = 0; r < 4; ++r) {
      int code = kbase + 16 * w + 4 * G + r;
      int d = 16 * nt + ln;
      atomicAdd(&dw_g[code * 64 + d], dwacc[nt][r]);
    }
  }
  creg += __shfl_xor(creg, 16, 64);
  creg += __shfl_xor(creg, 32, 64);
  if (G == 0) atomicAdd(&counts_g[kbase + 16 * w + ln], creg);
}

// ---------------- finalize ----------------
__device__ __forceinline__ float blk_sum(float v, float* red4) {
  #pragma unroll
  for (int off = 1; off < 64; off <<= 1) v += __shfl_xor(v, off, 64);
  __syncthreads();
  if ((threadIdx.x & 63) == 0) red4[threadIdx.x >> 6] = v;
  __syncthreads();
  return red4[0] + red4[1] + red4[2] + red4[3];
}

__global__ void k_stats(const float* __restrict__ counts_g, const float* __restrict__ ema_cs,
                        const float* __restrict__ usage, float* __restrict__ cs_g,
                        float* __restrict__ scal)
{
  __shared__ float red4[4];
  const int t = threadIdx.x;
  float4 c4 = ((const float4*)counts_g)[t];
  float4 e4 = ((const float4*)ema_cs)[t];
  float4 u4 = ((const float4*)usage)[t];
  float cnt[4] = {c4.x, c4.y, c4.z, c4.w};
  float ecs[4] = {e4.x, e4.y, e4.z, e4.w};
  float usg[4] = {u4.x, u4.y, u4.z, u4.w};
  float ncs[4], nu[4];
  float n_p = 0.f, snu_p = 0.f, ent_p = 0.f;
  #pragma unroll
  for (int j = 0; j < 4; ++j) {
    ncs[j] = fmaf(0.99f, ecs[j], 0.01f * cnt[j]);
    n_p += ncs[j];
    nu[j] = fmaf(0.99f, usg[j], 0.01f * cnt[j]);
    snu_p += nu[j];
    float avg = cnt[j] * (1.0f / 131072.0f);
    ent_p -= avg * logf(avg + 1e-10f);
  }
  float n = blk_sum(n_p, red4);
  float snu = blk_sum(snu_p, red4);
  float ent = blk_sum(ent_p, red4);
  float div_p = 0.f;
  float denom = n + 1024.0f * 1e-5f;
  float4 cso;
  float* csa = (float*)&cso;
  #pragma unroll
  for (int j = 0; j < 4; ++j) {
    csa[j] = (ncs[j] + 1e-5f) / denom * n;
    float up = nu[j] / (snu + 1e-5f);
    div_p -= up * logf(up + 1e-10f);
  }
  ((float4*)cs_g)[t] = cso;
  float dvr = blk_sum(div_p, red4);
  if (t == 0) { scal[0] = ent; scal[1] = dvr; }
}

__global__ void k_reg(const float* __restrict__ dw_g, const float* __restrict__ ema_w,
                      const float* __restrict__ cs_g, float* __restrict__ reg_g)
{
  int i = (blockIdx.x * 256 + threadIdx.x) * 2;
  float2 d2 = *(const float2*)(dw_g + i);
  float2 w2 = *(const float2*)(ema_w + i);
  float cs = cs_g[i >> 6];
  float v0 = fmaf(0.01f, d2.x, 0.99f * w2.x) / cs;
  float v1 = fmaf(0.01f, d2.y, 0.99f * w2.y) / cs;
  float p = v0 * v0 + v1 * v1;
  #pragma unroll
  for (int off = 1; off < 64; off <<= 1) p += __shfl_xor(p, off, 64);
  if ((threadIdx.x & 63) == 0) atomicAdd(reg_g, p);
}

__global__ void k_out(const float* __restrict__ sq_g, const float* __restrict__ reg_g,
                      const float* __restrict__ scal, float* __restrict__ out)
{
  if (threadIdx.x == 0) {
    float mse = sq_g[0] * (1.0f / 8388608.0f);
    float loss = 1.25f * mse + reg_g[0] + 0.8f * (scal[0] + scal[1]);
    out[NELEM] = loss;
    out[NELEM + 1] = expf(scal[0]);
  }
}

extern "C" void kernel_launch(void* const* d_in, const int* in_sizes, int n_in,
                              void* d_out, int out_size, void* d_ws, size_t ws_size,
                              hipStream_t stream)
{
  const float* x      = (const float*)d_in[0];
  const float* emb    = (const float*)d_in[1];
  const float* temp   = (const float*)d_in[2];
  const float* ema_cs = (const float*)d_in[3];
  const float* ema_w  = (const float*)d_in[4];
  const float* usage  = (const float*)d_in[5];
  float* out = (float*)d_out;
  float* ws  = (float*)d_ws;

  // workspace layout (floats)
  float* counts = ws;               // 1024
  float* dwv    = ws + 1024;        // 65536
  float* sq     = ws + 66560;       // 1
  float* reg    = ws + 66561;       // 1
  float* scal   = ws + 66562;       // 2 (ent, dvr)
  float* cs_g   = ws + 66576;       // 1024
  float* en2s   = ws + 67600;       // 1024
  float* b_g    = ws + 68624;       // 131072
  char* erh = (char*)(ws + 199696); // 128 KB each emb image
  char* erl = (char*)(ws + 232464);
  char* eth = (char*)(ws + 265232);
  char* etl = (char*)(ws + 298000);
  // x images (fast path): 16 MB each
  char* xrh = (char*)(ws + 330768);
  char* xrl = xrh + (size_t)16777216;
  char* xth = xrl + (size_t)16777216;
  char* xtl = xth + (size_t)16777216;
  const size_t need_fast = (size_t)330768 * 4 + 4ull * 16777216;  // ~68.4 MB

  hipMemsetAsync(ws, 0, 66564 * sizeof(float), stream);  // counts+dw+sq+reg+scal
  prep_emb<<<16, 256, 0, stream>>>(emb, temp, erh, erl, eth, etl, en2s);
  if (ws_size >= need_fast) {
    prep_x<<<2048, 256, 0, stream>>>(x, xrh, xrl, xth, xtl);
    k_main<<<NROWS / 64, 256, 0, stream>>>(x, temp, erh, erl, eth, etl, en2s, b_g, sq, out);
    k_dw_fast<<<1024, 256, 0, stream>>>(temp, erh, erl, xrh, xrl, xth, xtl, en2s, b_g, dwv, counts);
  } else {
    k_main<<<NROWS / 64, 256, 0, stream>>>(x, temp, erh, erl, eth, etl, en2s, b_g, sq, out);
    k_dw<<<1024, 256, 0, stream>>>(x, temp, erh, erl, en2s, b_g, dwv, counts);
  }
  k_stats<<<1, 256, 0, stream>>>(counts, ema_cs, usage, cs_g, scal);
  k_reg<<<128, 256, 0, stream>>>(dwv, ema_w, cs_g, reg);
  k_out<<<1, 64, 0, stream>>>(sq, reg, scal, out);
}